// Round 3
// baseline (37560.498 us; speedup 1.0000x reference)
//
#include <hip/hip_runtime.h>
#include <stdint.h>

typedef unsigned int u32;
typedef unsigned long long u64;

#define NPTS 8192

// ws byte offsets
#define WS_HIST4   0u        // u32[65536]: 16384 bins x 4 replicas (262144 B)
#define WS_STATE   262144u   // u32[8]: 0:b0 1:b1 2:base0 3:base1 4:ctr
#define WS_DC      262208u   // float dc
#define WS_SQ      262656u   // float[8192]
#define WS_ROWMAX  295424u   // u32 rowmax d2-bits[8192]
#define WS_RHOD    328192u   // double rho[8192]
#define WS_MINKEY  393728u   // u64 minkey[8192]
#define WS_CAND    459264u   // u64[CAP] candidates (raw<<32|w), ends ~2.56MB
#define CAP        262144u

#define K_RANK 1342177u  // floor(0.02f * fp32(N*N-1)); frac = 0.25 (validated r1/r2)

__device__ __forceinline__ u64 umin64(u64 a, u64 b) { return a < b ? a : b; }

__device__ __forceinline__ void tri_decode(int t, int& bi, int& bj) {
  int a = (int)((sqrtf(8.0f * (float)t + 1.0f) - 1.0f) * 0.5f);
  while ((a + 1) * (a + 2) / 2 <= t) ++a;
  while (a * (a + 1) / 2 > t) --a;
  int b = t - a * (a + 1) / 2;
  bi = 63 - a; bj = 63 - b;   // a>=b -> bi<=bj
}

// d2 key->bin: floor(d2*2^20)>>14 (exact: *2^20 is a power-of-2 scale, no rounding;
// bin b <=> raw in [as_uint(b/64), as_uint((b+1)/64)) -- dyadic boundaries exact)
__device__ __forceinline__ u32 bin_of(float d2v) {
  float kf = fminf(d2v * 1048576.0f, 2147483520.0f);
  return min(((u32)kf) >> 14, 16383u);
}

// 128x128 d2 tile; 256 threads, 8x8 frags; 4 phases of k=16, LDS double-buffered,
// register prefetch 2 phases ahead. One barrier per phase. fmaf chain order fixed
// (k ascending) => bit-identical d2 across all 4 pass kernels.
__device__ __forceinline__ void tile128(
    const float* __restrict__ X, const float* __restrict__ sq,
    float (*As)[16][132], float (*Bs)[16][132],
    int bi, int bj, int tx, int ty, float (&d2)[8][8])
{
  const int tid = threadIdx.x;
  const float4* Xv = reinterpret_cast<const float4*>(X);

  auto stage_load = [&](int p, float4 (&la)[2], float4 (&lb)[2]) {
#pragma unroll
    for (int rep = 0; rep < 2; ++rep) {
      int idx = rep * 256 + tid;        // [0,512): i=idx>>2 row, q=idx&3 k-quad
      int i = idx >> 2, q = idx & 3;
      la[rep] = Xv[(bi * 128 + i) * 16 + p * 4 + q];
      lb[rep] = Xv[(bj * 128 + i) * 16 + p * 4 + q];
    }
  };
  auto stage_write = [&](int buf, const float4 (&la)[2], const float4 (&lb)[2]) {
#pragma unroll
    for (int rep = 0; rep < 2; ++rep) {
      int idx = rep * 256 + tid;
      int i = idx >> 2, q = idx & 3;
      int col = ((((i >> 2) ^ (q >> 1)) << 2) | (i & 3));   // 2 lanes/bank = free
      float va[4] = {la[rep].x, la[rep].y, la[rep].z, la[rep].w};
      float vb[4] = {lb[rep].x, lb[rep].y, lb[rep].z, lb[rep].w};
#pragma unroll
      for (int j = 0; j < 4; ++j) {
        As[buf][4 * q + j][col] = va[j];
        Bs[buf][4 * q + j][col] = vb[j];
      }
    }
  };

  float acc[8][8] = {};
  float4 pa[2], pb[2], ca[2], cb[2];
  stage_load(0, pa, pb);
  stage_write(0, pa, pb);
  stage_load(1, ca, cb);                // prefetch phase 1
  __syncthreads();
#pragma unroll
  for (int p = 0; p < 4; ++p) {
    if (p < 3) {
      stage_write((p + 1) & 1, ca, cb); // write next phase into other buffer
      if (p < 2) stage_load(p + 2, ca, cb);  // refill prefetch regs
    }
    const int buf = p & 1;
#pragma unroll
    for (int k = 0; k < 16; ++k) {
      int c8 = k >> 3;
      float4 a0 = *reinterpret_cast<const float4*>(&As[buf][k][((2 * ty + 0) ^ c8) << 2]);
      float4 a1 = *reinterpret_cast<const float4*>(&As[buf][k][((2 * ty + 1) ^ c8) << 2]);
      float4 b0 = *reinterpret_cast<const float4*>(&Bs[buf][k][((2 * tx + 0) ^ c8) << 2]);
      float4 b1 = *reinterpret_cast<const float4*>(&Bs[buf][k][((2 * tx + 1) ^ c8) << 2]);
      float a[8] = {a0.x, a0.y, a0.z, a0.w, a1.x, a1.y, a1.z, a1.w};
      float b[8] = {b0.x, b0.y, b0.z, b0.w, b1.x, b1.y, b1.z, b1.w};
#pragma unroll
      for (int r = 0; r < 8; ++r)
#pragma unroll
        for (int c = 0; c < 8; ++c)
          acc[r][c] = fmaf(a[r], b[c], acc[r][c]);
    }
    __syncthreads();   // reads(p) done before next iter overwrites buf; writes(p+1) visible
  }

  float sqa[8], sqb[8];
#pragma unroll
  for (int r = 0; r < 8; ++r) sqa[r] = sq[bi * 128 + ty * 8 + r];
#pragma unroll
  for (int c = 0; c < 8; ++c) sqb[c] = sq[bj * 128 + tx * 8 + c];
#pragma unroll
  for (int r = 0; r < 8; ++r)
#pragma unroll
    for (int c = 0; c < 8; ++c)
      d2[r][c] = fmaxf((sqa[r] + sqb[c]) - 2.0f * acc[r][c], 0.0f);
}

__global__ __launch_bounds__(256) void k_init(u32* __restrict__ ws) {
  u32 t = blockIdx.x * 256u + threadIdx.x;   // 65536 threads
  ws[t] = 0u;                                // hist replicas
  if (t < 8u) ws[WS_STATE / 4 + t] = 0u;
  if (t < 8192u) {
    ws[WS_ROWMAX / 4 + t] = 0u;
    reinterpret_cast<double*>((char*)ws + WS_RHOD)[t] = 0.0;
    reinterpret_cast<u64*>((char*)ws + WS_MINKEY)[t] = ~0ull;
  }
}

__global__ __launch_bounds__(256) void k_sq(const float* __restrict__ X, float* __restrict__ sq) {
  int i = blockIdx.x * 256 + threadIdx.x;
  const float4* row = reinterpret_cast<const float4*>(X + i * 64);
  float s = 0.f;
#pragma unroll
  for (int q = 0; q < 16; ++q) {
    float4 v = row[q];
    s = fmaf(v.x, v.x, s); s = fmaf(v.y, v.y, s);
    s = fmaf(v.z, v.z, s); s = fmaf(v.w, v.w, s);
  }
  sq[i] = s;   // identical fma chain to tile dot(i,i) -> diagonal d2 == 0 exactly
}

// pass 1: global x4-replicated 16384-bin histogram of d2 keys + rowmax
__global__ __launch_bounds__(256, 4) void k_hist(
    const float* __restrict__ X, const float* __restrict__ sq, u32* __restrict__ ws)
{
  __shared__ __align__(16) float As[2][16][132];
  __shared__ __align__(16) float Bs[2][16][132];
  int bi, bj; tri_decode(blockIdx.x, bi, bj);
  const int tid = threadIdx.x;
  const int tx = tid & 15, ty = tid >> 4;
  float d2[8][8];
  tile128(X, sq, As, Bs, bi, bj, tx, ty, d2);

  const int ig0 = bi * 128 + ty * 8, jg0 = bj * 128 + tx * 8;

  // rowmax on d2 bits (uint order == float order for >=0)
  u32* rowmax = ws + WS_ROWMAX / 4;
  u32 rmA[8], rmB[8];
#pragma unroll
  for (int r = 0; r < 8; ++r) {
    u32 m = 0;
#pragma unroll
    for (int c = 0; c < 8; ++c) m = max(m, __float_as_uint(d2[r][c]));
    rmA[r] = m;
  }
#pragma unroll
  for (int c = 0; c < 8; ++c) {
    u32 m = 0;
#pragma unroll
    for (int r = 0; r < 8; ++r) m = max(m, __float_as_uint(d2[r][c]));
    rmB[c] = m;
  }
#pragma unroll
  for (int m = 1; m <= 8; m <<= 1)
#pragma unroll
    for (int r = 0; r < 8; ++r) rmA[r] = max(rmA[r], (u32)__shfl_xor((int)rmA[r], m));
  if ((tid & 15) == 0)
#pragma unroll
    for (int r = 0; r < 8; ++r) atomicMax(&rowmax[ig0 + r], rmA[r]);
#pragma unroll
  for (int m = 16; m <= 32; m <<= 1)
#pragma unroll
    for (int c = 0; c < 8; ++c) rmB[c] = max(rmB[c], (u32)__shfl_xor((int)rmB[c], m));
  if ((tid & 48) == 0)
#pragma unroll
    for (int c = 0; c < 8; ++c) atomicMax(&rowmax[jg0 + c], rmB[c]);

  u32* H = ws;
  const bool offd = (bi < bj);
  const u32 rep4 = (u32)(tid & 3);
#pragma unroll
  for (int r = 0; r < 8; ++r)
#pragma unroll
    for (int c = 0; c < 8; ++c) {
      int ig = ig0 + r, jg = jg0 + c;
      u32 w = offd ? 2u : (ig < jg ? 2u : (ig == jg ? 1u : 0u));
      if (w) atomicAdd(&H[(bin_of(d2[r][c]) << 2) | rep4], w);
    }
}

// pick bins containing order-stats K and K+1 (weighted), with exclusive bases
__global__ __launch_bounds__(1024) void k_sel1(u32* __restrict__ ws) {
  __shared__ u32 part[1024];
  const int t = threadIdx.x;
  const u32* H = ws;
  u32* st = ws + WS_STATE / 4;
  u32 cnt16[16];
  u32 s = 0;
#pragma unroll
  for (int e = 0; e < 16; ++e) {
    u32 b = (u32)t * 16u + (u32)e;
    u32 v = H[4 * b] + H[4 * b + 1] + H[4 * b + 2] + H[4 * b + 3];
    cnt16[e] = v; s += v;
  }
  part[t] = s;
  __syncthreads();
  if (t == 0) {
    u32 run = 0;
    for (int x = 0; x < 1024; ++x) { u32 c = part[x]; part[x] = run; run += c; }
  }
  __syncthreads();
  u32 cum = part[t];
#pragma unroll
  for (int e = 0; e < 16; ++e) {
    u32 b = (u32)t * 16u + (u32)e;
    u32 c = cnt16[e];
    if (cum <= K_RANK && K_RANK < cum + c)           { st[0] = b; st[2] = cum; }
    if (cum <= K_RANK + 1u && K_RANK + 1u < cum + c) { st[1] = b; st[3] = cum; }
    cum += c;
  }
}

// pass 2: collect raw d2 bits of values in bins {b0,b1} (wave-ballot compaction)
__global__ __launch_bounds__(256, 4) void k_collect(
    const float* __restrict__ X, const float* __restrict__ sq, u32* __restrict__ ws)
{
  __shared__ __align__(16) float As[2][16][132];
  __shared__ __align__(16) float Bs[2][16][132];
  int bi, bj; tri_decode(blockIdx.x, bi, bj);
  const int tid = threadIdx.x;
  const int tx = tid & 15, ty = tid >> 4;
  float d2[8][8];
  tile128(X, sq, As, Bs, bi, bj, tx, ty, d2);

  u32* st = ws + WS_STATE / 4;
  const u32 b0 = st[0], b1 = st[1];
  u32* ctr = st + 4;
  u64* cand = reinterpret_cast<u64*>((char*)ws + WS_CAND);
  const int ig0 = bi * 128 + ty * 8, jg0 = bj * 128 + tx * 8;
  const bool offd = (bi < bj);
  const int lane = tid & 63;
#pragma unroll
  for (int r = 0; r < 8; ++r)
#pragma unroll
    for (int c = 0; c < 8; ++c) {
      int ig = ig0 + r, jg = jg0 + c;
      u32 w = offd ? 2u : (ig < jg ? 2u : (ig == jg ? 1u : 0u));
      u32 bin = bin_of(d2[r][c]);
      bool ic = w && (bin == b0 || bin == b1);
      u64 m = __ballot(ic);
      if (m) {
        int leader = __ffsll((long long)m) - 1;
        u32 base = 0;
        if (lane == leader) base = atomicAdd(ctr, (u32)__popcll(m));
        base = (u32)__shfl((int)base, leader);
        if (ic) {
          u32 pos = base + (u32)__popcll(m & ((1ull << lane) - 1ull));
          if (pos < CAP)
            cand[pos] = (((u64)__float_as_uint(d2[r][c])) << 32) | (u64)w;
        }
      }
    }
}

// LDS histogram zoom over candidate raw bits within bin b; returns raw of order-stat `rank`
__device__ u32 zoom(const u64* __restrict__ cand, u32 M, u32 b, u32 base, u32 rank,
                    u32* h, u32* msg) {
  u32 lo = __float_as_uint((float)b * 0.015625f);
  u32 hi = __float_as_uint((float)(b + 1) * 0.015625f);
  u32 need = rank - base;
  while (hi - lo > 1u) {
    u32 range = hi - lo;
    int sh = 0;
    while ((2048u << sh) < range) ++sh;      // range <= ~2^30 -> sh <= 19, no overflow
    for (u32 i = threadIdx.x; i < 2048u; i += blockDim.x) h[i] = 0;
    __syncthreads();
    for (u32 i = threadIdx.x; i < M; i += blockDim.x) {
      u64 cw = cand[i];
      u32 raw = (u32)(cw >> 32);
      if (raw >= lo && raw < hi) atomicAdd(&h[(raw - lo) >> sh], (u32)(cw & 3u));
    }
    __syncthreads();
    if (threadIdx.x == 0) {
      u32 cum = 0, bb = 0;
      while (bb < 2047u && cum + h[bb] <= need) { cum += h[bb]; ++bb; }
      msg[0] = bb; msg[1] = cum;
    }
    __syncthreads();
    u32 bb = msg[0], sub = msg[1];
    need -= sub;
    u32 nlo = lo + (bb << sh);
    hi = min(hi, nlo + (1u << sh));
    lo = nlo;
    __syncthreads();
  }
  return lo;
}

__global__ __launch_bounds__(1024) void k_fsel(u32* __restrict__ ws) {
  __shared__ u32 h[2048];
  __shared__ u32 msg[2];
  u32* st = ws + WS_STATE / 4;
  const u64* cand = reinterpret_cast<const u64*>((const char*)ws + WS_CAND);
  u32 M = min(st[4], CAP);
  u32 v0 = zoom(cand, M, st[0], st[2], K_RANK, h, msg);
  u32 v1 = zoom(cand, M, st[1], st[3], K_RANK + 1u, h, msg);
  if (threadIdx.x == 0) {
    float w0 = sqrtf(__uint_as_float(v0));   // exact dist order stats
    float w1 = sqrtf(__uint_as_float(v1));
    double dc = 0.75 * (double)w0 + 0.25 * (double)w1;
    *reinterpret_cast<float*>((char*)ws + WS_DC) = (float)dc;
  }
}

__global__ __launch_bounds__(256, 4) void k_rho(
    const float* __restrict__ X, const float* __restrict__ sq, u32* __restrict__ ws)
{
  __shared__ __align__(16) float As[2][16][132];
  __shared__ __align__(16) float Bs[2][16][132];
  int bi, bj; tri_decode(blockIdx.x, bi, bj);
  const int tid = threadIdx.x;
  const int tx = tid & 15, ty = tid >> 4;
  float d2[8][8];
  tile128(X, sq, As, Bs, bi, bj, tx, ty, d2);
  const float dcf = *reinterpret_cast<const float*>((const char*)ws + WS_DC);
  const float inv2 = 1.0f / (dcf * dcf);
  const int ig0 = bi * 128 + ty * 8, jg0 = bj * 128 + tx * 8;
  const bool diag = (bi == bj);
  float rA[8] = {}, rB[8] = {};
#pragma unroll
  for (int r = 0; r < 8; ++r)
#pragma unroll
    for (int c = 0; c < 8; ++c) {
      float t = __expf(-(d2[r][c] * inv2));
      if (!diag) { rA[r] += t; rB[c] += t; }
      else {
        int ig = ig0 + r, jg = jg0 + c;
        if (ig < jg) { rA[r] += t; rB[c] += t; }
        else if (ig == jg) rA[r] += t;
      }
    }
  double* rhod = reinterpret_cast<double*>((char*)ws + WS_RHOD);
#pragma unroll
  for (int m = 1; m <= 8; m <<= 1)
#pragma unroll
    for (int r = 0; r < 8; ++r) rA[r] += __shfl_xor(rA[r], m);
  if ((tid & 15) == 0)
#pragma unroll
    for (int r = 0; r < 8; ++r) atomicAdd(&rhod[ig0 + r], (double)rA[r]);
#pragma unroll
  for (int m = 16; m <= 32; m <<= 1)
#pragma unroll
    for (int c = 0; c < 8; ++c) rB[c] += __shfl_xor(rB[c], m);
  if ((tid & 48) == 0)
#pragma unroll
    for (int c = 0; c < 8; ++c) atomicAdd(&rhod[jg0 + c], (double)rB[c]);
}

__global__ __launch_bounds__(256, 4) void k_delta(
    const float* __restrict__ X, const float* __restrict__ sq, u32* __restrict__ ws)
{
  __shared__ __align__(16) float As[2][16][132];
  __shared__ __align__(16) float Bs[2][16][132];
  int bi, bj; tri_decode(blockIdx.x, bi, bj);
  const int tid = threadIdx.x;
  const int tx = tid & 15, ty = tid >> 4;
  float d2[8][8];
  tile128(X, sq, As, Bs, bi, bj, tx, ty, d2);
  const double* rhod = reinterpret_cast<const double*>((const char*)ws + WS_RHOD);
  const int ig0 = bi * 128 + ty * 8, jg0 = bj * 128 + tx * 8;
  float ri[8], rj[8];
#pragma unroll
  for (int r = 0; r < 8; ++r) ri[r] = (float)rhod[ig0 + r];   // float compare == r2's validated path
#pragma unroll
  for (int c = 0; c < 8; ++c) rj[c] = (float)rhod[jg0 + c];
  u64 bA[8], bB[8];
#pragma unroll
  for (int r = 0; r < 8; ++r) { bA[r] = ~0ull; bB[r] = ~0ull; }
  const bool offd = (bi < bj);
#pragma unroll
  for (int r = 0; r < 8; ++r)
#pragma unroll
    for (int c = 0; c < 8; ++c) {
      int ig = ig0 + r, jg = jg0 + c;
      if (offd || ig < jg) {
        // sqrt here: reproduces reference argmin tie semantics exactly
        u64 kb = ((u64)__float_as_uint(sqrtf(d2[r][c]))) << 32;
        if (rj[c] > ri[r]) bA[r] = umin64(bA[r], kb | (u64)(u32)jg);
        if (ri[r] > rj[c]) bB[c] = umin64(bB[c], kb | (u64)(u32)ig);
      }
    }
  u64* mk = reinterpret_cast<u64*>((char*)ws + WS_MINKEY);
#pragma unroll
  for (int m = 1; m <= 8; m <<= 1)
#pragma unroll
    for (int r = 0; r < 8; ++r) bA[r] = umin64(bA[r], __shfl_xor(bA[r], m));
  if ((tid & 15) == 0)
#pragma unroll
    for (int r = 0; r < 8; ++r) atomicMin(&mk[ig0 + r], bA[r]);
#pragma unroll
  for (int m = 16; m <= 32; m <<= 1)
#pragma unroll
    for (int c = 0; c < 8; ++c) bB[c] = umin64(bB[c], __shfl_xor(bB[c], m));
  if ((tid & 48) == 0)
#pragma unroll
    for (int c = 0; c < 8; ++c) atomicMin(&mk[jg0 + c], bB[c]);
}

__global__ __launch_bounds__(1024) void k_labels(
    const u32* __restrict__ ws, const float* __restrict__ rtp,
    const float* __restrict__ dtp, int* __restrict__ out)
{
  __shared__ int   nhd_s[NPTS];
  __shared__ short lab_s[NPTS];
  __shared__ int   tsum[1024];
  const int t = threadIdx.x;
  const float rt = rtp[0], dt = dtp[0];
  const u64* mk = reinterpret_cast<const u64*>((const char*)ws + WS_MINKEY);
  const u32* rowmax = ws + WS_ROWMAX / 4;
  const double* rhod = reinterpret_cast<const double*>((const char*)ws + WS_RHOD);
  int cnt = 0;
  short loc[8];
#pragma unroll
  for (int e = 0; e < 8; ++e) {
    int i = t * 8 + e;
    u64 key = mk[i];
    bool hh = (key != ~0ull);
    float delta = hh ? __uint_as_float((u32)(key >> 32))
                     : sqrtf(__uint_as_float(rowmax[i]));
    int nh = hh ? (int)(u32)(key & 0xffffffffull) : i;
    nhd_s[i] = nh;
    bool isc = ((float)rhod[i] > rt) && (delta > dt);
    loc[e] = isc ? (short)cnt : (short)-1;
    cnt += isc ? 1 : 0;
  }
  tsum[t] = cnt;
  __syncthreads();
  if (t == 0) {
    int run = 0;
    for (int x = 0; x < 1024; ++x) { int c = tsum[x]; tsum[x] = run; run += c; }
  }
  __syncthreads();
  int base = tsum[t];
#pragma unroll
  for (int e = 0; e < 8; ++e) {
    int i = t * 8 + e;
    lab_s[i] = (loc[e] >= 0) ? (short)(loc[e] + base) : (short)-1;
  }
  __syncthreads();
#pragma unroll
  for (int e = 0; e < 8; ++e) {
    int i = t * 8 + e;
    int cur = i;
    while (lab_s[cur] < 0 && nhd_s[cur] != cur) cur = nhd_s[cur];
    out[i] = (int)lab_s[cur];
  }
}

extern "C" void kernel_launch(void* const* d_in, const int* in_sizes, int n_in,
                              void* d_out, int out_size, void* d_ws, size_t ws_size,
                              hipStream_t stream)
{
  (void)in_sizes; (void)n_in; (void)out_size; (void)ws_size;
  const float* X  = (const float*)d_in[0];
  const float* rt = (const float*)d_in[1];
  const float* dt = (const float*)d_in[2];
  int* out = (int*)d_out;
  u32* ws = (u32*)d_ws;
  float* sq = (float*)((char*)d_ws + WS_SQ);

  const int NTRI = 64 * 65 / 2;   // 2080 triangular tiles, no dead blocks

  k_init<<<256, 256, 0, stream>>>(ws);
  k_sq<<<32, 256, 0, stream>>>(X, sq);

  k_hist<<<NTRI, 256, 0, stream>>>(X, sq, ws);
  k_sel1<<<1, 1024, 0, stream>>>(ws);
  k_collect<<<NTRI, 256, 0, stream>>>(X, sq, ws);
  k_fsel<<<1, 1024, 0, stream>>>(ws);

  k_rho<<<NTRI, 256, 0, stream>>>(X, sq, ws);
  k_delta<<<NTRI, 256, 0, stream>>>(X, sq, ws);
  k_labels<<<1, 1024, 0, stream>>>(ws, rt, dt, out);
}

// Round 4
// 631.840 us; speedup vs baseline: 59.4463x; 59.4463x over previous
//
#include <hip/hip_runtime.h>
#include <stdint.h>

typedef unsigned int u32;
typedef unsigned long long u64;

#define NPTS 8192
#define NTRI 2080            // 64*65/2 triangular 128x128 tiles

// ws byte offsets
#define WS_HIST    0u        // u32[8192] global histogram
#define WS_STATE   32768u    // u32[8]: 0:b0 1:b1 2:base0 3:base1 4:ctr
#define WS_DC      32800u    // float dc
#define WS_SQ      33024u    // float[8192]
#define WS_ROWMAX  65792u    // u32[8192] rowmax d2-bits
#define WS_RHOD    98560u    // double[8192]
#define WS_MINKEY  164096u   // u64[8192]
#define WS_CAND    229632u   // u64[CAP] candidates (raw<<32|w)
#define CAP        65536u
#define WS_S       1048576ull  // float[NTRI*16384] d2 tile store = 136314880 B

#define K_RANK 1342177u  // floor(0.02f * fp32(N*N-1)); frac = 0.25 (validated r1-r3)

__device__ __forceinline__ u64 umin64(u64 a, u64 b) { return a < b ? a : b; }

__device__ __forceinline__ void tri_decode(int t, int& bi, int& bj) {
  int a = (int)((sqrtf(8.0f * (float)t + 1.0f) - 1.0f) * 0.5f);
  while ((a + 1) * (a + 2) / 2 <= t) ++a;
  while (a * (a + 1) / 2 > t) --a;
  int b = t - a * (a + 1) / 2;
  bi = 63 - a; bj = 63 - b;   // a>=b -> bi<=bj
}

// 8192 bins over key=floor(d2*2^20): bin b <=> d2 in [b/32,(b+1)/32) (dyadic, exact)
__device__ __forceinline__ u32 bin_of(float d2v) {
  float kf = fminf(d2v * 1048576.0f, 2147483520.0f);
  return min(((u32)kf) >> 15, 8191u);
}

// ===== r2-exact tile128: 2 phases of k=32, loads consumed immediately (NO persistent
// prefetch regs -- r3's spill lesson: 64-acc kernel has no VGPR headroom). =====
__device__ __forceinline__ void tile128(
    const float* __restrict__ X, const float* __restrict__ sq,
    float (*As)[132], float (*Bs)[132],
    int bi, int bj, int tx, int ty, float (&d2)[8][8])
{
  const int tid = threadIdx.x;
  const float4* Xv = reinterpret_cast<const float4*>(X);
  float acc[8][8] = {};
  for (int ph = 0; ph < 2; ++ph) {
    if (ph) __syncthreads();          // protect LDS before overwrite
#pragma unroll
    for (int rep = 0; rep < 4; ++rep) {
      int idx = rep * 256 + tid;      // 0..1023
      int i   = idx >> 3;             // row 0..127
      int q   = idx & 7;              // local k-quad
      int col = (((i >> 2) ^ (q >> 1)) << 2) | (i & 3);   // 2 lanes/bank = free
      float4 va = Xv[(bi * 128 + i) * 16 + ph * 8 + q];
      As[4*q+0][col] = va.x; As[4*q+1][col] = va.y; As[4*q+2][col] = va.z; As[4*q+3][col] = va.w;
      float4 vb = Xv[(bj * 128 + i) * 16 + ph * 8 + q];
      Bs[4*q+0][col] = vb.x; Bs[4*q+1][col] = vb.y; Bs[4*q+2][col] = vb.z; Bs[4*q+3][col] = vb.w;
    }
    __syncthreads();
#pragma unroll
    for (int c8 = 0; c8 < 4; ++c8) {
#pragma unroll
      for (int u = 0; u < 8; ++u) {
        int k = c8 * 8 + u;
        float4 a0 = *reinterpret_cast<const float4*>(&As[k][((2*ty+0) ^ c8) << 2]);
        float4 a1 = *reinterpret_cast<const float4*>(&As[k][((2*ty+1) ^ c8) << 2]);
        float4 b0 = *reinterpret_cast<const float4*>(&Bs[k][((2*tx+0) ^ c8) << 2]);
        float4 b1 = *reinterpret_cast<const float4*>(&Bs[k][((2*tx+1) ^ c8) << 2]);
        float a[8] = {a0.x,a0.y,a0.z,a0.w,a1.x,a1.y,a1.z,a1.w};
        float b[8] = {b0.x,b0.y,b0.z,b0.w,b1.x,b1.y,b1.z,b1.w};
#pragma unroll
        for (int r = 0; r < 8; ++r)
#pragma unroll
          for (int c = 0; c < 8; ++c)
            acc[r][c] = fmaf(a[r], b[c], acc[r][c]);
      }
    }
  }
  float sqa[8], sqb[8];
#pragma unroll
  for (int r = 0; r < 8; ++r) sqa[r] = sq[bi * 128 + ty * 8 + r];
#pragma unroll
  for (int c = 0; c < 8; ++c) sqb[c] = sq[bj * 128 + tx * 8 + c];
#pragma unroll
  for (int r = 0; r < 8; ++r)
#pragma unroll
    for (int c = 0; c < 8; ++c)
      d2[r][c] = fmaxf((sqa[r] + sqb[c]) - 2.0f * acc[r][c], 0.0f);
}

// ===== per-element pass bodies (shared by recompute and stored-d2 kernels) =====

__device__ __forceinline__ void collect_body(
    float (&d2)[8][8], int bi, int bj, int tx, int ty, u32* __restrict__ ws)
{
  u32* st = ws + WS_STATE / 4;
  const u32 b0 = st[0], b1 = st[1];
  u32* ctr = st + 4;
  u64* cand = reinterpret_cast<u64*>((char*)ws + WS_CAND);
  const int ig0 = bi * 128 + ty * 8, jg0 = bj * 128 + tx * 8;
  const bool offd = (bi < bj);
  const int lane = threadIdx.x & 63;
#pragma unroll
  for (int r = 0; r < 8; ++r)
#pragma unroll
    for (int c = 0; c < 8; ++c) {
      int ig = ig0 + r, jg = jg0 + c;
      u32 w = offd ? 2u : (ig < jg ? 2u : (ig == jg ? 1u : 0u));
      u32 bin = bin_of(d2[r][c]);
      bool ic = w && (bin == b0 || bin == b1);
      u64 m = __ballot(ic);
      if (m) {
        int leader = __ffsll((long long)m) - 1;
        u32 base = 0;
        if (lane == leader) base = atomicAdd(ctr, (u32)__popcll(m));
        base = (u32)__shfl((int)base, leader);
        if (ic) {
          u32 pos = base + (u32)__popcll(m & ((1ull << lane) - 1ull));
          if (pos < CAP)
            cand[pos] = (((u64)__float_as_uint(d2[r][c])) << 32) | (u64)w;
        }
      }
    }
}

__device__ __forceinline__ void rho_body(
    float (&d2)[8][8], int bi, int bj, int tx, int ty, u32* __restrict__ ws)
{
  const int tid = threadIdx.x;
  const float dcf = *reinterpret_cast<const float*>((const char*)ws + WS_DC);
  const float inv2 = 1.0f / (dcf * dcf);
  const int ig0 = bi * 128 + ty * 8, jg0 = bj * 128 + tx * 8;
  const bool diag = (bi == bj);
  float rA[8] = {}, rB[8] = {};
#pragma unroll
  for (int r = 0; r < 8; ++r)
#pragma unroll
    for (int c = 0; c < 8; ++c) {
      float t = __expf(-(d2[r][c] * inv2));
      if (!diag) { rA[r] += t; rB[c] += t; }
      else {
        int ig = ig0 + r, jg = jg0 + c;
        if (ig < jg) { rA[r] += t; rB[c] += t; }
        else if (ig == jg) rA[r] += t;
      }
    }
  double* rhod = reinterpret_cast<double*>((char*)ws + WS_RHOD);
#pragma unroll
  for (int m = 1; m <= 8; m <<= 1)
#pragma unroll
    for (int r = 0; r < 8; ++r) rA[r] += __shfl_xor(rA[r], m);
  if ((tid & 15) == 0)
#pragma unroll
    for (int r = 0; r < 8; ++r) atomicAdd(&rhod[ig0 + r], (double)rA[r]);
#pragma unroll
  for (int m = 16; m <= 32; m <<= 1)
#pragma unroll
    for (int c = 0; c < 8; ++c) rB[c] += __shfl_xor(rB[c], m);
  if ((tid & 48) == 0)
#pragma unroll
    for (int c = 0; c < 8; ++c) atomicAdd(&rhod[jg0 + c], (double)rB[c]);
}

__device__ __forceinline__ void delta_body(
    float (&d2)[8][8], int bi, int bj, int tx, int ty, u32* __restrict__ ws)
{
  const int tid = threadIdx.x;
  const double* rhod = reinterpret_cast<const double*>((const char*)ws + WS_RHOD);
  const int ig0 = bi * 128 + ty * 8, jg0 = bj * 128 + tx * 8;
  float ri[8], rj[8];
#pragma unroll
  for (int r = 0; r < 8; ++r) ri[r] = (float)rhod[ig0 + r];
#pragma unroll
  for (int c = 0; c < 8; ++c) rj[c] = (float)rhod[jg0 + c];
  u64 bA[8], bB[8];
#pragma unroll
  for (int r = 0; r < 8; ++r) { bA[r] = ~0ull; bB[r] = ~0ull; }
  const bool offd = (bi < bj);
#pragma unroll
  for (int r = 0; r < 8; ++r)
#pragma unroll
    for (int c = 0; c < 8; ++c) {
      int ig = ig0 + r, jg = jg0 + c;
      if (offd || ig < jg) {
        // sqrt: reproduces reference dist-domain argmin tie semantics exactly
        u64 kb = ((u64)__float_as_uint(sqrtf(d2[r][c]))) << 32;
        if (rj[c] > ri[r]) bA[r] = umin64(bA[r], kb | (u64)(u32)jg);
        if (ri[r] > rj[c]) bB[c] = umin64(bB[c], kb | (u64)(u32)ig);
      }
    }
  u64* mk = reinterpret_cast<u64*>((char*)ws + WS_MINKEY);
#pragma unroll
  for (int m = 1; m <= 8; m <<= 1)
#pragma unroll
    for (int r = 0; r < 8; ++r) bA[r] = umin64(bA[r], __shfl_xor(bA[r], m));
  if ((tid & 15) == 0)
#pragma unroll
    for (int r = 0; r < 8; ++r) atomicMin(&mk[ig0 + r], bA[r]);
#pragma unroll
  for (int m = 16; m <= 32; m <<= 1)
#pragma unroll
    for (int c = 0; c < 8; ++c) bB[c] = umin64(bB[c], __shfl_xor(bB[c], m));
  if ((tid & 48) == 0)
#pragma unroll
    for (int c = 0; c < 8; ++c) atomicMin(&mk[jg0 + c], bB[c]);
}

// load a stored tile (coalesced: lane-consecutive float4 at fixed q)
__device__ __forceinline__ void load_tile(
    const float4* __restrict__ S4, float (&d2)[8][8])
{
  const float4* tS = S4 + (size_t)blockIdx.x * 4096 + threadIdx.x;
#pragma unroll
  for (int q = 0; q < 16; ++q) {
    float4 v = tS[q * 256];
    int r = q >> 1, c0 = (q & 1) * 4;
    d2[r][c0+0] = v.x; d2[r][c0+1] = v.y; d2[r][c0+2] = v.z; d2[r][c0+3] = v.w;
  }
}

// ===== kernels =====

__global__ __launch_bounds__(256) void k_init(u32* __restrict__ ws) {
  u32 t = blockIdx.x * 256u + threadIdx.x;   // 8192 threads
  ws[t] = 0u;                                // global hist
  if (t < 8u) ws[WS_STATE / 4 + t] = 0u;
  ws[WS_ROWMAX / 4 + t] = 0u;
  reinterpret_cast<double*>((char*)ws + WS_RHOD)[t] = 0.0;
  reinterpret_cast<u64*>((char*)ws + WS_MINKEY)[t] = ~0ull;
}

__global__ __launch_bounds__(256) void k_sq(const float* __restrict__ X, float* __restrict__ sq) {
  int i = blockIdx.x * 256 + threadIdx.x;
  const float4* row = reinterpret_cast<const float4*>(X + i * 64);
  float s = 0.f;
#pragma unroll
  for (int q = 0; q < 16; ++q) {
    float4 v = row[q];
    s = fmaf(v.x, v.x, s); s = fmaf(v.y, v.y, s);
    s = fmaf(v.z, v.z, s); s = fmaf(v.w, v.w, s);
  }
  sq[i] = s;   // identical fma chain to tile dot(i,i) -> diagonal d2 == 0 exactly
}

// THE compute pass: d2 tile + optional d2 store + rowmax + 8192-bin hist (LDS reused)
__global__ __launch_bounds__(256, 4) void k_hist(
    const float* __restrict__ X, const float* __restrict__ sq,
    u32* __restrict__ ws, float4* __restrict__ S4)
{
  __shared__ __align__(16) char smem[33792];
  float (*As)[132] = reinterpret_cast<float(*)[132]>(smem);
  float (*Bs)[132] = reinterpret_cast<float(*)[132]>(smem + 16896);
  u32* h = reinterpret_cast<u32*>(smem);           // 8192 u32 = 32 KB, reused post-compute
  int bi, bj; tri_decode(blockIdx.x, bi, bj);
  const int tid = threadIdx.x;
  const int tx = tid & 15, ty = tid >> 4;
  float d2[8][8];
  tile128(X, sq, As, Bs, bi, bj, tx, ty, d2);

  if (S4) {                                        // store d2 (coalesced float4)
    float4* tS = S4 + (size_t)blockIdx.x * 4096 + tid;
#pragma unroll
    for (int q = 0; q < 16; ++q) {
      int r = q >> 1, c0 = (q & 1) * 4;
      tS[q * 256] = make_float4(d2[r][c0+0], d2[r][c0+1], d2[r][c0+2], d2[r][c0+3]);
    }
  }

  const int ig0 = bi * 128 + ty * 8, jg0 = bj * 128 + tx * 8;
  u32* rowmax = ws + WS_ROWMAX / 4;
  u32 rmA[8], rmB[8];
#pragma unroll
  for (int r = 0; r < 8; ++r) {
    u32 m = 0;
#pragma unroll
    for (int c = 0; c < 8; ++c) m = max(m, __float_as_uint(d2[r][c]));
    rmA[r] = m;
  }
#pragma unroll
  for (int c = 0; c < 8; ++c) {
    u32 m = 0;
#pragma unroll
    for (int r = 0; r < 8; ++r) m = max(m, __float_as_uint(d2[r][c]));
    rmB[c] = m;
  }
#pragma unroll
  for (int m = 1; m <= 8; m <<= 1)
#pragma unroll
    for (int r = 0; r < 8; ++r) rmA[r] = max(rmA[r], (u32)__shfl_xor((int)rmA[r], m));
  if ((tid & 15) == 0)
#pragma unroll
    for (int r = 0; r < 8; ++r) atomicMax(&rowmax[ig0 + r], rmA[r]);
#pragma unroll
  for (int m = 16; m <= 32; m <<= 1)
#pragma unroll
    for (int c = 0; c < 8; ++c) rmB[c] = max(rmB[c], (u32)__shfl_xor((int)rmB[c], m));
  if ((tid & 48) == 0)
#pragma unroll
    for (int c = 0; c < 8; ++c) atomicMax(&rowmax[jg0 + c], rmB[c]);

  __syncthreads();                                 // done reading tile LDS
  for (int i = tid; i < 8192; i += 256) h[i] = 0;
  __syncthreads();
  const bool offd = (bi < bj);
#pragma unroll
  for (int r = 0; r < 8; ++r)
#pragma unroll
    for (int c = 0; c < 8; ++c) {
      int ig = ig0 + r, jg = jg0 + c;
      u32 w = offd ? 2u : (ig < jg ? 2u : (ig == jg ? 1u : 0u));
      if (w) atomicAdd(&h[bin_of(d2[r][c])], w);
    }
  __syncthreads();
  for (int b = tid; b < 8192; b += 256) {
    u32 v = h[b];
    if (v) atomicAdd(&ws[b], v);
  }
}

__global__ __launch_bounds__(1024) void k_sel1(u32* __restrict__ ws) {
  __shared__ u32 part[1024];
  const int t = threadIdx.x;
  const u32* H = ws;
  u32* st = ws + WS_STATE / 4;
  u32 cnt8[8];
  u32 s = 0;
#pragma unroll
  for (int e = 0; e < 8; ++e) { cnt8[e] = H[t * 8 + e]; s += cnt8[e]; }
  part[t] = s;
  __syncthreads();
  if (t == 0) {
    u32 run = 0;
    for (int x = 0; x < 1024; ++x) { u32 c = part[x]; part[x] = run; run += c; }
  }
  __syncthreads();
  u32 cum = part[t];
#pragma unroll
  for (int e = 0; e < 8; ++e) {
    u32 b = (u32)t * 8u + (u32)e;
    u32 c = cnt8[e];
    if (cum <= K_RANK && K_RANK < cum + c)           { st[0] = b; st[2] = cum; }
    if (cum <= K_RANK + 1u && K_RANK + 1u < cum + c) { st[1] = b; st[3] = cum; }
    cum += c;
  }
}

__global__ __launch_bounds__(256, 4) void k_collectR(
    const float* __restrict__ X, const float* __restrict__ sq, u32* __restrict__ ws)
{
  __shared__ __align__(16) char smem[33792];
  float (*As)[132] = reinterpret_cast<float(*)[132]>(smem);
  float (*Bs)[132] = reinterpret_cast<float(*)[132]>(smem + 16896);
  int bi, bj; tri_decode(blockIdx.x, bi, bj);
  const int tx = threadIdx.x & 15, ty = threadIdx.x >> 4;
  float d2[8][8];
  tile128(X, sq, As, Bs, bi, bj, tx, ty, d2);
  collect_body(d2, bi, bj, tx, ty, ws);
}

__global__ __launch_bounds__(256) void k_collectS(
    const float4* __restrict__ S4, u32* __restrict__ ws)
{
  int bi, bj; tri_decode(blockIdx.x, bi, bj);
  const int tx = threadIdx.x & 15, ty = threadIdx.x >> 4;
  float d2[8][8];
  load_tile(S4, d2);
  collect_body(d2, bi, bj, tx, ty, ws);
}

// zoom: LDS histogram refinement over candidate raw bits within bin b
__device__ u32 zoom(const u64* __restrict__ cand, u32 M, u32 b, u32 base, u32 rank,
                    u32* h, u32* msg) {
  u32 lo = __float_as_uint((float)b * 0.03125f);
  u32 hi = __float_as_uint((float)(b + 1) * 0.03125f);
  u32 need = rank - base;
  while (hi - lo > 1u) {
    u32 range = hi - lo;
    int sh = 0;
    while ((2048u << sh) < range) ++sh;
    for (u32 i = threadIdx.x; i < 2048u; i += blockDim.x) h[i] = 0;
    __syncthreads();
    for (u32 i = threadIdx.x; i < M; i += blockDim.x) {
      u64 cw = cand[i];
      u32 raw = (u32)(cw >> 32);
      if (raw >= lo && raw < hi) atomicAdd(&h[(raw - lo) >> sh], (u32)(cw & 3u));
    }
    __syncthreads();
    if (threadIdx.x == 0) {
      u32 cum = 0, bb = 0;
      while (bb < 2047u && cum + h[bb] <= need) { cum += h[bb]; ++bb; }
      msg[0] = bb; msg[1] = cum;
    }
    __syncthreads();
    u32 bb = msg[0], sub = msg[1];
    need -= sub;
    u32 nlo = lo + (bb << sh);
    hi = min(hi, nlo + (1u << sh));
    lo = nlo;
    __syncthreads();
  }
  return lo;
}

__global__ __launch_bounds__(1024) void k_fsel(u32* __restrict__ ws) {
  __shared__ u32 h[2048];
  __shared__ u32 msg[2];
  u32* st = ws + WS_STATE / 4;
  const u64* cand = reinterpret_cast<const u64*>((const char*)ws + WS_CAND);
  u32 M = min(st[4], CAP);
  u32 v0 = zoom(cand, M, st[0], st[2], K_RANK, h, msg);
  u32 v1 = zoom(cand, M, st[1], st[3], K_RANK + 1u, h, msg);
  if (threadIdx.x == 0) {
    float w0 = sqrtf(__uint_as_float(v0));
    float w1 = sqrtf(__uint_as_float(v1));
    double dc = 0.75 * (double)w0 + 0.25 * (double)w1;
    *reinterpret_cast<float*>((char*)ws + WS_DC) = (float)dc;
  }
}

__global__ __launch_bounds__(256, 4) void k_rhoR(
    const float* __restrict__ X, const float* __restrict__ sq, u32* __restrict__ ws)
{
  __shared__ __align__(16) char smem[33792];
  float (*As)[132] = reinterpret_cast<float(*)[132]>(smem);
  float (*Bs)[132] = reinterpret_cast<float(*)[132]>(smem + 16896);
  int bi, bj; tri_decode(blockIdx.x, bi, bj);
  const int tx = threadIdx.x & 15, ty = threadIdx.x >> 4;
  float d2[8][8];
  tile128(X, sq, As, Bs, bi, bj, tx, ty, d2);
  rho_body(d2, bi, bj, tx, ty, ws);
}

__global__ __launch_bounds__(256) void k_rhoS(
    const float4* __restrict__ S4, u32* __restrict__ ws)
{
  int bi, bj; tri_decode(blockIdx.x, bi, bj);
  const int tx = threadIdx.x & 15, ty = threadIdx.x >> 4;
  float d2[8][8];
  load_tile(S4, d2);
  rho_body(d2, bi, bj, tx, ty, ws);
}

__global__ __launch_bounds__(256, 4) void k_deltaR(
    const float* __restrict__ X, const float* __restrict__ sq, u32* __restrict__ ws)
{
  __shared__ __align__(16) char smem[33792];
  float (*As)[132] = reinterpret_cast<float(*)[132]>(smem);
  float (*Bs)[132] = reinterpret_cast<float(*)[132]>(smem + 16896);
  int bi, bj; tri_decode(blockIdx.x, bi, bj);
  const int tx = threadIdx.x & 15, ty = threadIdx.x >> 4;
  float d2[8][8];
  tile128(X, sq, As, Bs, bi, bj, tx, ty, d2);
  delta_body(d2, bi, bj, tx, ty, ws);
}

__global__ __launch_bounds__(256) void k_deltaS(
    const float4* __restrict__ S4, u32* __restrict__ ws)
{
  int bi, bj; tri_decode(blockIdx.x, bi, bj);
  const int tx = threadIdx.x & 15, ty = threadIdx.x >> 4;
  float d2[8][8];
  load_tile(S4, d2);
  delta_body(d2, bi, bj, tx, ty, ws);
}

__global__ __launch_bounds__(1024) void k_labels(
    const u32* __restrict__ ws, const float* __restrict__ rtp,
    const float* __restrict__ dtp, int* __restrict__ out)
{
  __shared__ int   nhd_s[NPTS];
  __shared__ short lab_s[NPTS];
  __shared__ int   tsum[1024];
  const int t = threadIdx.x;
  const float rt = rtp[0], dt = dtp[0];
  const u64* mk = reinterpret_cast<const u64*>((const char*)ws + WS_MINKEY);
  const u32* rowmax = ws + WS_ROWMAX / 4;
  const double* rhod = reinterpret_cast<const double*>((const char*)ws + WS_RHOD);
  int cnt = 0;
  short loc[8];
#pragma unroll
  for (int e = 0; e < 8; ++e) {
    int i = t * 8 + e;
    u64 key = mk[i];
    bool hh = (key != ~0ull);
    float delta = hh ? __uint_as_float((u32)(key >> 32))
                     : sqrtf(__uint_as_float(rowmax[i]));
    int nh = hh ? (int)(u32)(key & 0xffffffffull) : i;
    nhd_s[i] = nh;
    bool isc = ((float)rhod[i] > rt) && (delta > dt);
    loc[e] = isc ? (short)cnt : (short)-1;
    cnt += isc ? 1 : 0;
  }
  tsum[t] = cnt;
  __syncthreads();
  if (t == 0) {
    int run = 0;
    for (int x = 0; x < 1024; ++x) { int c = tsum[x]; tsum[x] = run; run += c; }
  }
  __syncthreads();
  int base = tsum[t];
#pragma unroll
  for (int e = 0; e < 8; ++e) {
    int i = t * 8 + e;
    lab_s[i] = (loc[e] >= 0) ? (short)(loc[e] + base) : (short)-1;
  }
  __syncthreads();
#pragma unroll
  for (int e = 0; e < 8; ++e) {
    int i = t * 8 + e;
    int cur = i;
    while (lab_s[cur] < 0 && nhd_s[cur] != cur) cur = nhd_s[cur];
    out[i] = (int)lab_s[cur];
  }
}

extern "C" void kernel_launch(void* const* d_in, const int* in_sizes, int n_in,
                              void* d_out, int out_size, void* d_ws, size_t ws_size,
                              hipStream_t stream)
{
  (void)in_sizes; (void)n_in; (void)out_size;
  const float* X  = (const float*)d_in[0];
  const float* rt = (const float*)d_in[1];
  const float* dt = (const float*)d_in[2];
  int* out = (int*)d_out;
  u32* ws = (u32*)d_ws;
  float* sq = (float*)((char*)d_ws + WS_SQ);

  const bool big = ws_size >= (size_t)(WS_S + (u64)NTRI * 16384ull * 4ull);
  float4* S4 = big ? reinterpret_cast<float4*>((char*)d_ws + WS_S) : nullptr;

  k_init<<<32, 256, 0, stream>>>(ws);
  k_sq<<<32, 256, 0, stream>>>(X, sq);

  k_hist<<<NTRI, 256, 0, stream>>>(X, sq, ws, S4);
  k_sel1<<<1, 1024, 0, stream>>>(ws);
  if (big) k_collectS<<<NTRI, 256, 0, stream>>>(S4, ws);
  else     k_collectR<<<NTRI, 256, 0, stream>>>(X, sq, ws);
  k_fsel<<<1, 1024, 0, stream>>>(ws);
  if (big) k_rhoS<<<NTRI, 256, 0, stream>>>(S4, ws);
  else     k_rhoR<<<NTRI, 256, 0, stream>>>(X, sq, ws);
  if (big) k_deltaS<<<NTRI, 256, 0, stream>>>(S4, ws);
  else     k_deltaR<<<NTRI, 256, 0, stream>>>(X, sq, ws);
  k_labels<<<1, 1024, 0, stream>>>(ws, rt, dt, out);
}

// Round 6
// 467.976 us; speedup vs baseline: 80.2615x; 1.3502x over previous
//
#include <hip/hip_runtime.h>
#include <stdint.h>

typedef unsigned int u32;
typedef unsigned long long u64;

#define NPTS 8192
#define NTRI 2080            // 64*65/2 triangular 128x128 tiles

// ws byte offsets
#define WS_HIST    0u        // u32[8192] global histogram
#define WS_STATE   32768u    // u32[8]: 0:b0 1:b1 2:base0 3:base1 4:ctr
#define WS_DC      32800u    // float dc
#define WS_SQ      33024u    // float[8192]
#define WS_ROWMAX  65792u    // u32[8192] rowmax d2-bits
#define WS_RHOD    98560u    // double[8192]
#define WS_MINKEY  164096u   // u64[8192]
#define WS_CAND    229632u   // u64[CAP] candidates (raw<<32|w)
#define CAP        65536u
#define WS_S       1048576ull  // float[NTRI*16384] d2 tile store = 136314880 B

#define K_RANK 1342177u  // floor(0.02f * fp32(N*N-1)); frac = 0.25 (validated r1-r4)

__device__ __forceinline__ u64 umin64(u64 a, u64 b) { return a < b ? a : b; }

__device__ __forceinline__ void tri_decode(int t, int& bi, int& bj) {
  int a = (int)((sqrtf(8.0f * (float)t + 1.0f) - 1.0f) * 0.5f);
  while ((a + 1) * (a + 2) / 2 <= t) ++a;
  while (a * (a + 1) / 2 > t) --a;
  int b = t - a * (a + 1) / 2;
  bi = 63 - a; bj = 63 - b;   // a>=b -> bi<=bj
}

// 8192 bins over key=floor(d2*2^20): bin b <=> d2 in [b/32,(b+1)/32) (dyadic, exact)
__device__ __forceinline__ u32 bin_of(float d2v) {
  float kf = fminf(d2v * 1048576.0f, 2147483520.0f);
  return min(((u32)kf) >> 15, 8191u);
}

// exclusive prefix over 1024 threads (16 waves of 64). aux: u32[40] LDS.
// 2 barriers; replaces r4's thread-0 serial scans (the 164us k_fsel pathology).
__device__ __forceinline__ u32 block_exscan_1024(u32 v, u32* aux, u32& total) {
  const int lane = threadIdx.x & 63, wave = threadIdx.x >> 6;
  u32 inc = v;
#pragma unroll
  for (int m = 1; m < 64; m <<= 1) {
    u32 o = (u32)__shfl_up((int)inc, m, 64);
    if (lane >= m) inc += o;
  }
  if (lane == 63) aux[wave] = inc;
  __syncthreads();
  if (wave == 0) {
    u32 wv = (lane < 16) ? aux[lane] : 0u;
    u32 winc = wv;
#pragma unroll
    for (int m = 1; m < 16; m <<= 1) {
      u32 o = (u32)__shfl_up((int)winc, m, 64);
      if (lane >= m) winc += o;
    }
    if (lane < 16) aux[16 + lane] = winc - wv;   // wave-exclusive base
    if (lane == 15) aux[33] = winc;              // grand total
  }
  __syncthreads();
  total = aux[33];
  return aux[16 + wave] + (inc - v);
}

// ===== r2-exact tile128: 2 phases of k=32, loads consumed immediately (NO persistent
// prefetch regs -- r3's spill lesson: 64-acc kernel has no VGPR headroom). =====
__device__ __forceinline__ void tile128(
    const float* __restrict__ X, const float* __restrict__ sq,
    float (*As)[132], float (*Bs)[132],
    int bi, int bj, int tx, int ty, float (&d2)[8][8])
{
  const int tid = threadIdx.x;
  const float4* Xv = reinterpret_cast<const float4*>(X);
  float acc[8][8] = {};
  for (int ph = 0; ph < 2; ++ph) {
    if (ph) __syncthreads();          // protect LDS before overwrite
#pragma unroll
    for (int rep = 0; rep < 4; ++rep) {
      int idx = rep * 256 + tid;      // 0..1023
      int i   = idx >> 3;             // row 0..127
      int q   = idx & 7;              // local k-quad
      int col = (((i >> 2) ^ (q >> 1)) << 2) | (i & 3);   // 2 lanes/bank = free
      float4 va = Xv[(bi * 128 + i) * 16 + ph * 8 + q];
      As[4*q+0][col] = va.x; As[4*q+1][col] = va.y; As[4*q+2][col] = va.z; As[4*q+3][col] = va.w;
      float4 vb = Xv[(bj * 128 + i) * 16 + ph * 8 + q];
      Bs[4*q+0][col] = vb.x; Bs[4*q+1][col] = vb.y; Bs[4*q+2][col] = vb.z; Bs[4*q+3][col] = vb.w;
    }
    __syncthreads();
#pragma unroll
    for (int c8 = 0; c8 < 4; ++c8) {
#pragma unroll
      for (int u = 0; u < 8; ++u) {
        int k = c8 * 8 + u;
        float4 a0 = *reinterpret_cast<const float4*>(&As[k][((2*ty+0) ^ c8) << 2]);
        float4 a1 = *reinterpret_cast<const float4*>(&As[k][((2*ty+1) ^ c8) << 2]);
        float4 b0 = *reinterpret_cast<const float4*>(&Bs[k][((2*tx+0) ^ c8) << 2]);
        float4 b1 = *reinterpret_cast<const float4*>(&Bs[k][((2*tx+1) ^ c8) << 2]);
        float a[8] = {a0.x,a0.y,a0.z,a0.w,a1.x,a1.y,a1.z,a1.w};
        float b[8] = {b0.x,b0.y,b0.z,b0.w,b1.x,b1.y,b1.z,b1.w};
#pragma unroll
        for (int r = 0; r < 8; ++r)
#pragma unroll
          for (int c = 0; c < 8; ++c)
            acc[r][c] = fmaf(a[r], b[c], acc[r][c]);
      }
    }
  }
  float sqa[8], sqb[8];
#pragma unroll
  for (int r = 0; r < 8; ++r) sqa[r] = sq[bi * 128 + ty * 8 + r];
#pragma unroll
  for (int c = 0; c < 8; ++c) sqb[c] = sq[bj * 128 + tx * 8 + c];
#pragma unroll
  for (int r = 0; r < 8; ++r)
#pragma unroll
    for (int c = 0; c < 8; ++c)
      d2[r][c] = fmaxf((sqa[r] + sqb[c]) - 2.0f * acc[r][c], 0.0f);
}

// ===== per-element pass bodies (shared by recompute and stored-d2 kernels) =====

__device__ __forceinline__ void collect_body(
    float (&d2)[8][8], int bi, int bj, int tx, int ty, u32* __restrict__ ws)
{
  u32* st = ws + WS_STATE / 4;
  const u32 b0 = st[0], b1 = st[1];
  u32* ctr = st + 4;
  u64* cand = reinterpret_cast<u64*>((char*)ws + WS_CAND);
  const int ig0 = bi * 128 + ty * 8, jg0 = bj * 128 + tx * 8;
  const bool offd = (bi < bj);
  const int lane = threadIdx.x & 63;
#pragma unroll
  for (int r = 0; r < 8; ++r)
#pragma unroll
    for (int c = 0; c < 8; ++c) {
      int ig = ig0 + r, jg = jg0 + c;
      u32 w = offd ? 2u : (ig < jg ? 2u : (ig == jg ? 1u : 0u));
      u32 bin = bin_of(d2[r][c]);
      bool ic = w && (bin == b0 || bin == b1);
      u64 m = __ballot(ic);
      if (m) {
        int leader = __ffsll((long long)m) - 1;
        u32 base = 0;
        if (lane == leader) base = atomicAdd(ctr, (u32)__popcll(m));
        base = (u32)__shfl((int)base, leader);
        if (ic) {
          u32 pos = base + (u32)__popcll(m & ((1ull << lane) - 1ull));
          if (pos < CAP)
            cand[pos] = (((u64)__float_as_uint(d2[r][c])) << 32) | (u64)w;
        }
      }
    }
}

__device__ __forceinline__ void rho_body(
    float (&d2)[8][8], int bi, int bj, int tx, int ty, u32* __restrict__ ws)
{
  const int tid = threadIdx.x;
  const float dcf = *reinterpret_cast<const float*>((const char*)ws + WS_DC);
  const float inv2 = 1.0f / (dcf * dcf);
  const int ig0 = bi * 128 + ty * 8, jg0 = bj * 128 + tx * 8;
  const bool diag = (bi == bj);
  float rA[8] = {}, rB[8] = {};
#pragma unroll
  for (int r = 0; r < 8; ++r)
#pragma unroll
    for (int c = 0; c < 8; ++c) {
      float t = __expf(-(d2[r][c] * inv2));
      if (!diag) { rA[r] += t; rB[c] += t; }
      else {
        int ig = ig0 + r, jg = jg0 + c;
        if (ig < jg) { rA[r] += t; rB[c] += t; }
        else if (ig == jg) rA[r] += t;
      }
    }
  double* rhod = reinterpret_cast<double*>((char*)ws + WS_RHOD);
#pragma unroll
  for (int m = 1; m <= 8; m <<= 1)
#pragma unroll
    for (int r = 0; r < 8; ++r) rA[r] += __shfl_xor(rA[r], m);
  if ((tid & 15) == 0)
#pragma unroll
    for (int r = 0; r < 8; ++r) atomicAdd(&rhod[ig0 + r], (double)rA[r]);
#pragma unroll
  for (int m = 16; m <= 32; m <<= 1)
#pragma unroll
    for (int c = 0; c < 8; ++c) rB[c] += __shfl_xor(rB[c], m);
  if ((tid & 48) == 0)
#pragma unroll
    for (int c = 0; c < 8; ++c) atomicAdd(&rhod[jg0 + c], (double)rB[c]);
}

__device__ __forceinline__ void delta_body(
    float (&d2)[8][8], int bi, int bj, int tx, int ty, u32* __restrict__ ws)
{
  const int tid = threadIdx.x;
  const double* rhod = reinterpret_cast<const double*>((const char*)ws + WS_RHOD);
  const int ig0 = bi * 128 + ty * 8, jg0 = bj * 128 + tx * 8;
  float ri[8], rj[8];
#pragma unroll
  for (int r = 0; r < 8; ++r) ri[r] = (float)rhod[ig0 + r];
#pragma unroll
  for (int c = 0; c < 8; ++c) rj[c] = (float)rhod[jg0 + c];
  u64 bA[8], bB[8];
#pragma unroll
  for (int r = 0; r < 8; ++r) { bA[r] = ~0ull; bB[r] = ~0ull; }
  const bool offd = (bi < bj);
#pragma unroll
  for (int r = 0; r < 8; ++r)
#pragma unroll
    for (int c = 0; c < 8; ++c) {
      int ig = ig0 + r, jg = jg0 + c;
      if (offd || ig < jg) {
        // sqrt: reproduces reference dist-domain argmin tie semantics exactly
        u64 kb = ((u64)__float_as_uint(sqrtf(d2[r][c]))) << 32;
        if (rj[c] > ri[r]) bA[r] = umin64(bA[r], kb | (u64)(u32)jg);
        if (ri[r] > rj[c]) bB[c] = umin64(bB[c], kb | (u64)(u32)ig);
      }
    }
  u64* mk = reinterpret_cast<u64*>((char*)ws + WS_MINKEY);
#pragma unroll
  for (int m = 1; m <= 8; m <<= 1)
#pragma unroll
    for (int r = 0; r < 8; ++r) bA[r] = umin64(bA[r], __shfl_xor(bA[r], m));
  if ((tid & 15) == 0)
#pragma unroll
    for (int r = 0; r < 8; ++r) atomicMin(&mk[ig0 + r], bA[r]);
#pragma unroll
  for (int m = 16; m <= 32; m <<= 1)
#pragma unroll
    for (int c = 0; c < 8; ++c) bB[c] = umin64(bB[c], __shfl_xor(bB[c], m));
  if ((tid & 48) == 0)
#pragma unroll
    for (int c = 0; c < 8; ++c) atomicMin(&mk[jg0 + c], bB[c]);
}

// load a stored tile (coalesced: lane-consecutive float4 at fixed q)
__device__ __forceinline__ void load_tile(
    const float4* __restrict__ S4, float (&d2)[8][8])
{
  const float4* tS = S4 + (size_t)blockIdx.x * 4096 + threadIdx.x;
#pragma unroll
  for (int q = 0; q < 16; ++q) {
    float4 v = tS[q * 256];
    int r = q >> 1, c0 = (q & 1) * 4;
    d2[r][c0+0] = v.x; d2[r][c0+1] = v.y; d2[r][c0+2] = v.z; d2[r][c0+3] = v.w;
  }
}

// ===== kernels =====

__global__ __launch_bounds__(256) void k_init(u32* __restrict__ ws) {
  u32 t = blockIdx.x * 256u + threadIdx.x;   // 8192 threads
  ws[t] = 0u;                                // global hist
  if (t < 8u) ws[WS_STATE / 4 + t] = 0u;
  ws[WS_ROWMAX / 4 + t] = 0u;
  reinterpret_cast<double*>((char*)ws + WS_RHOD)[t] = 0.0;
  reinterpret_cast<u64*>((char*)ws + WS_MINKEY)[t] = ~0ull;
}

__global__ __launch_bounds__(256) void k_sq(const float* __restrict__ X, float* __restrict__ sq) {
  int i = blockIdx.x * 256 + threadIdx.x;
  const float4* row = reinterpret_cast<const float4*>(X + i * 64);
  float s = 0.f;
#pragma unroll
  for (int q = 0; q < 16; ++q) {
    float4 v = row[q];
    s = fmaf(v.x, v.x, s); s = fmaf(v.y, v.y, s);
    s = fmaf(v.z, v.z, s); s = fmaf(v.w, v.w, s);
  }
  sq[i] = s;   // identical fma chain to tile dot(i,i) -> diagonal d2 == 0 exactly
}

// THE compute pass: d2 tile + optional d2 store + rowmax + 8192-bin hist (LDS reused)
__global__ __launch_bounds__(256, 4) void k_hist(
    const float* __restrict__ X, const float* __restrict__ sq,
    u32* __restrict__ ws, float4* __restrict__ S4)
{
  __shared__ __align__(16) char smem[33792];
  float (*As)[132] = reinterpret_cast<float(*)[132]>(smem);
  float (*Bs)[132] = reinterpret_cast<float(*)[132]>(smem + 16896);
  u32* h = reinterpret_cast<u32*>(smem);           // 8192 u32 = 32 KB, reused post-compute
  int bi, bj; tri_decode(blockIdx.x, bi, bj);
  const int tid = threadIdx.x;
  const int tx = tid & 15, ty = tid >> 4;
  float d2[8][8];
  tile128(X, sq, As, Bs, bi, bj, tx, ty, d2);

  if (S4) {                                        // store d2 (coalesced float4)
    float4* tS = S4 + (size_t)blockIdx.x * 4096 + tid;
#pragma unroll
    for (int q = 0; q < 16; ++q) {
      int r = q >> 1, c0 = (q & 1) * 4;
      tS[q * 256] = make_float4(d2[r][c0+0], d2[r][c0+1], d2[r][c0+2], d2[r][c0+3]);
    }
  }

  const int ig0 = bi * 128 + ty * 8, jg0 = bj * 128 + tx * 8;
  u32* rowmax = ws + WS_ROWMAX / 4;
  u32 rmA[8], rmB[8];
#pragma unroll
  for (int r = 0; r < 8; ++r) {
    u32 m = 0;
#pragma unroll
    for (int c = 0; c < 8; ++c) m = max(m, __float_as_uint(d2[r][c]));
    rmA[r] = m;
  }
#pragma unroll
  for (int c = 0; c < 8; ++c) {
    u32 m = 0;
#pragma unroll
    for (int r = 0; r < 8; ++r) m = max(m, __float_as_uint(d2[r][c]));
    rmB[c] = m;
  }
#pragma unroll
  for (int m = 1; m <= 8; m <<= 1)
#pragma unroll
    for (int r = 0; r < 8; ++r) rmA[r] = max(rmA[r], (u32)__shfl_xor((int)rmA[r], m));
  if ((tid & 15) == 0)
#pragma unroll
    for (int r = 0; r < 8; ++r) atomicMax(&rowmax[ig0 + r], rmA[r]);
#pragma unroll
  for (int m = 16; m <= 32; m <<= 1)
#pragma unroll
    for (int c = 0; c < 8; ++c) rmB[c] = max(rmB[c], (u32)__shfl_xor((int)rmB[c], m));
  if ((tid & 48) == 0)
#pragma unroll
    for (int c = 0; c < 8; ++c) atomicMax(&rowmax[jg0 + c], rmB[c]);

  __syncthreads();                                 // done reading tile LDS
  for (int i = tid; i < 8192; i += 256) h[i] = 0;
  __syncthreads();
  const bool offd = (bi < bj);
#pragma unroll
  for (int r = 0; r < 8; ++r)
#pragma unroll
    for (int c = 0; c < 8; ++c) {
      int ig = ig0 + r, jg = jg0 + c;
      u32 w = offd ? 2u : (ig < jg ? 2u : (ig == jg ? 1u : 0u));
      if (w) atomicAdd(&h[bin_of(d2[r][c])], w);
    }
  __syncthreads();
  for (int b = tid; b < 8192; b += 256) {
    u32 v = h[b];
    if (v) atomicAdd(&ws[b], v);
  }
}

// parallel: each thread owns 8 bins; block exscan over thread sums; local locate
__global__ __launch_bounds__(1024) void k_sel1(u32* __restrict__ ws) {
  __shared__ u32 aux[40];
  const int t = threadIdx.x;
  const u32* H = ws;
  u32* st = ws + WS_STATE / 4;
  u32 cnt8[8];
  u32 s = 0;
#pragma unroll
  for (int e = 0; e < 8; ++e) { cnt8[e] = H[t * 8 + e]; s += cnt8[e]; }
  u32 total;
  u32 cum = block_exscan_1024(s, aux, total);
#pragma unroll
  for (int e = 0; e < 8; ++e) {
    u32 b = (u32)t * 8u + (u32)e;
    u32 c = cnt8[e];
    if (cum <= K_RANK && K_RANK < cum + c)           { st[0] = b; st[2] = cum; }
    if (cum <= K_RANK + 1u && K_RANK + 1u < cum + c) { st[1] = b; st[3] = cum; }
    cum += c;
  }
}

__global__ __launch_bounds__(256, 4) void k_collectR(
    const float* __restrict__ X, const float* __restrict__ sq, u32* __restrict__ ws)
{
  __shared__ __align__(16) char smem[33792];
  float (*As)[132] = reinterpret_cast<float(*)[132]>(smem);
  float (*Bs)[132] = reinterpret_cast<float(*)[132]>(smem + 16896);
  int bi, bj; tri_decode(blockIdx.x, bi, bj);
  const int tx = threadIdx.x & 15, ty = threadIdx.x >> 4;
  float d2[8][8];
  tile128(X, sq, As, Bs, bi, bj, tx, ty, d2);
  collect_body(d2, bi, bj, tx, ty, ws);
}

__global__ __launch_bounds__(256) void k_collectS(
    const float4* __restrict__ S4, u32* __restrict__ ws)
{
  int bi, bj; tri_decode(blockIdx.x, bi, bj);
  const int tx = threadIdx.x & 15, ty = threadIdx.x >> 4;
  float d2[8][8];
  load_tile(S4, d2);
  collect_body(d2, bi, bj, tx, ty, ws);
}

// zoom: LDS histogram refinement over candidate raw bits within bin b.
// 8192-bin hist => 1 iteration typical; bin-locate is a parallel block scan.
__device__ u32 zoom(const u64* __restrict__ cand, u32 M, u32 b, u32 base, u32 rank,
                    u32* h, u32* aux) {
  u32 lo = __float_as_uint((float)b * 0.03125f);
  u32 hi = __float_as_uint((float)(b + 1) * 0.03125f);
  u32 need = rank - base;
  while (hi - lo > 1u) {
    u32 range = hi - lo;
    int sh = 0;
    while ((8192u << sh) < range) ++sh;
    for (u32 i = threadIdx.x; i < 8192u; i += 1024u) h[i] = 0;
    __syncthreads();
    for (u32 i = threadIdx.x; i < M; i += 1024u) {
      u64 cw = cand[i];
      u32 raw = (u32)(cw >> 32);
      if (raw >= lo && raw < hi) atomicAdd(&h[(raw - lo) >> sh], (u32)(cw & 3u));
    }
    __syncthreads();
    u32 loc[8];
    u32 s = 0;
#pragma unroll
    for (int e = 0; e < 8; ++e) { loc[e] = h[threadIdx.x * 8u + e]; s += loc[e]; }
    u32 total;
    u32 pre = block_exscan_1024(s, aux, total);
    if (need >= pre && need < pre + s) {      // exactly one thread matches
      u32 cum = pre;
#pragma unroll
      for (int e = 0; e < 8; ++e) {
        if (need >= cum && need < cum + loc[e]) { aux[36] = threadIdx.x * 8u + (u32)e; aux[37] = cum; }
        cum += loc[e];
      }
    }
    __syncthreads();
    u32 bb = aux[36], sub = aux[37];
    need -= sub;
    u32 nlo = lo + (bb << sh);
    hi = min(hi, nlo + (1u << sh));
    lo = nlo;
    __syncthreads();
  }
  return lo;
}

__global__ __launch_bounds__(1024) void k_fsel(u32* __restrict__ ws) {
  __shared__ u32 h[8192];
  __shared__ u32 aux[40];
  u32* st = ws + WS_STATE / 4;
  const u64* cand = reinterpret_cast<const u64*>((const char*)ws + WS_CAND);
  u32 M = min(st[4], CAP);
  u32 v0 = zoom(cand, M, st[0], st[2], K_RANK, h, aux);
  u32 v1 = zoom(cand, M, st[1], st[3], K_RANK + 1u, h, aux);
  if (threadIdx.x == 0) {
    float w0 = sqrtf(__uint_as_float(v0));
    float w1 = sqrtf(__uint_as_float(v1));
    double dc = 0.75 * (double)w0 + 0.25 * (double)w1;
    *reinterpret_cast<float*>((char*)ws + WS_DC) = (float)dc;
  }
}

__global__ __launch_bounds__(256, 4) void k_rhoR(
    const float* __restrict__ X, const float* __restrict__ sq, u32* __restrict__ ws)
{
  __shared__ __align__(16) char smem[33792];
  float (*As)[132] = reinterpret_cast<float(*)[132]>(smem);
  float (*Bs)[132] = reinterpret_cast<float(*)[132]>(smem + 16896);
  int bi, bj; tri_decode(blockIdx.x, bi, bj);
  const int tx = threadIdx.x & 15, ty = threadIdx.x >> 4;
  float d2[8][8];
  tile128(X, sq, As, Bs, bi, bj, tx, ty, d2);
  rho_body(d2, bi, bj, tx, ty, ws);
}

__global__ __launch_bounds__(256) void k_rhoS(
    const float4* __restrict__ S4, u32* __restrict__ ws)
{
  int bi, bj; tri_decode(blockIdx.x, bi, bj);
  const int tx = threadIdx.x & 15, ty = threadIdx.x >> 4;
  float d2[8][8];
  load_tile(S4, d2);
  rho_body(d2, bi, bj, tx, ty, ws);
}

__global__ __launch_bounds__(256, 4) void k_deltaR(
    const float* __restrict__ X, const float* __restrict__ sq, u32* __restrict__ ws)
{
  __shared__ __align__(16) char smem[33792];
  float (*As)[132] = reinterpret_cast<float(*)[132]>(smem);
  float (*Bs)[132] = reinterpret_cast<float(*)[132]>(smem + 16896);
  int bi, bj; tri_decode(blockIdx.x, bi, bj);
  const int tx = threadIdx.x & 15, ty = threadIdx.x >> 4;
  float d2[8][8];
  tile128(X, sq, As, Bs, bi, bj, tx, ty, d2);
  delta_body(d2, bi, bj, tx, ty, ws);
}

__global__ __launch_bounds__(256) void k_deltaS(
    const float4* __restrict__ S4, u32* __restrict__ ws)
{
  int bi, bj; tri_decode(blockIdx.x, bi, bj);
  const int tx = threadIdx.x & 15, ty = threadIdx.x >> 4;
  float d2[8][8];
  load_tile(S4, d2);
  delta_body(d2, bi, bj, tx, ty, ws);
}

__global__ __launch_bounds__(1024) void k_labels(
    const u32* __restrict__ ws, const float* __restrict__ rtp,
    const float* __restrict__ dtp, int* __restrict__ out)
{
  __shared__ int   nhd_s[NPTS];
  __shared__ short lab_s[NPTS];
  __shared__ u32   aux[40];
  const int t = threadIdx.x;
  const float rt = rtp[0], dt = dtp[0];
  const u64* mk = reinterpret_cast<const u64*>((const char*)ws + WS_MINKEY);
  const u32* rowmax = ws + WS_ROWMAX / 4;
  const double* rhod = reinterpret_cast<const double*>((const char*)ws + WS_RHOD);
  u32 cnt = 0;
  short loc[8];
#pragma unroll
  for (int e = 0; e < 8; ++e) {
    int i = t * 8 + e;
    u64 key = mk[i];
    bool hh = (key != ~0ull);
    float delta = hh ? __uint_as_float((u32)(key >> 32))
                     : sqrtf(__uint_as_float(rowmax[i]));
    int nh = hh ? (int)(u32)(key & 0xffffffffull) : i;
    nhd_s[i] = nh;
    bool isc = ((float)rhod[i] > rt) && (delta > dt);
    loc[e] = isc ? (short)cnt : (short)-1;
    cnt += isc ? 1u : 0u;
  }
  u32 total;
  u32 base = block_exscan_1024(cnt, aux, total);   // parallel scan (was thread-0 serial)
#pragma unroll
  for (int e = 0; e < 8; ++e) {
    int i = t * 8 + e;
    lab_s[i] = (loc[e] >= 0) ? (short)(loc[e] + (int)base) : (short)-1;
  }
  __syncthreads();
#pragma unroll
  for (int e = 0; e < 8; ++e) {
    int i = t * 8 + e;
    int cur = i;
    while (lab_s[cur] < 0 && nhd_s[cur] != cur) cur = nhd_s[cur];
    out[i] = (int)lab_s[cur];
  }
}

extern "C" void kernel_launch(void* const* d_in, const int* in_sizes, int n_in,
                              void* d_out, int out_size, void* d_ws, size_t ws_size,
                              hipStream_t stream)
{
  (void)in_sizes; (void)n_in; (void)out_size;
  const float* X  = (const float*)d_in[0];
  const float* rt = (const float*)d_in[1];
  const float* dt = (const float*)d_in[2];
  int* out = (int*)d_out;
  u32* ws = (u32*)d_ws;
  float* sq = (float*)((char*)d_ws + WS_SQ);

  const bool big = ws_size >= (size_t)(WS_S + (u64)NTRI * 16384ull * 4ull);
  float4* S4 = big ? reinterpret_cast<float4*>((char*)d_ws + WS_S) : nullptr;

  k_init<<<32, 256, 0, stream>>>(ws);
  k_sq<<<32, 256, 0, stream>>>(X, sq);

  k_hist<<<NTRI, 256, 0, stream>>>(X, sq, ws, S4);
  k_sel1<<<1, 1024, 0, stream>>>(ws);
  if (big) k_collectS<<<NTRI, 256, 0, stream>>>(S4, ws);
  else     k_collectR<<<NTRI, 256, 0, stream>>>(X, sq, ws);
  k_fsel<<<1, 1024, 0, stream>>>(ws);
  if (big) k_rhoS<<<NTRI, 256, 0, stream>>>(S4, ws);
  else     k_rhoR<<<NTRI, 256, 0, stream>>>(X, sq, ws);
  if (big) k_deltaS<<<NTRI, 256, 0, stream>>>(S4, ws);
  else     k_deltaR<<<NTRI, 256, 0, stream>>>(X, sq, ws);
  k_labels<<<1, 1024, 0, stream>>>(ws, rt, dt, out);
}

// Round 7
// 403.485 us; speedup vs baseline: 93.0901x; 1.1598x over previous
//
#include <hip/hip_runtime.h>
#include <stdint.h>

typedef unsigned int u32;
typedef unsigned long long u64;

#define NPTS 8192
#define NTRI 2080            // 64*65/2 triangular 128x128 tiles
#define NSLICE 16u           // hist slices (blockIdx&15) to cut atomic ping-pong

// ws byte offsets
#define WS_HIST    0u        // u32[16][8192] sliced global hist = 524288 B
#define WS_STATE   524288u   // u32[8]: 0:b0 1:b1 2:base0 3:base1 4:ctr
#define WS_DC      524320u   // float dc
#define WS_SQ      524800u   // float[8192] -> 557568
#define WS_ROWMAX  557568u   // u32[8192] rowmax d2-bits -> 590336
#define WS_RHOD    590336u   // double[8192] -> 655872
#define WS_MINKEY  655872u   // u64[8192] -> 721408
#define WS_CAND    721408u   // u64[CAP] -> 983552 (< 1 MB boundary)
#define CAP        32768u    // ~9K expected candidates -> 3.5x margin
#define WS_S       1048576ull  // float[NTRI*16384] d2 tile store = 136314880 B

#define K_RANK 1342177u  // floor(0.02f * fp32(N*N-1)); frac = 0.25 (validated r1-r6)

__device__ __forceinline__ u64 umin64(u64 a, u64 b) { return a < b ? a : b; }

__device__ __forceinline__ void tri_decode(int t, int& bi, int& bj) {
  int a = (int)((sqrtf(8.0f * (float)t + 1.0f) - 1.0f) * 0.5f);
  while ((a + 1) * (a + 2) / 2 <= t) ++a;
  while (a * (a + 1) / 2 > t) --a;
  int b = t - a * (a + 1) / 2;
  bi = 63 - a; bj = 63 - b;   // a>=b -> bi<=bj
}

// 8192 bins over key=floor(d2*2^20): bin b <=> d2 in [b/32,(b+1)/32) (dyadic, exact)
__device__ __forceinline__ u32 bin_of(float d2v) {
  float kf = fminf(d2v * 1048576.0f, 2147483520.0f);
  return min(((u32)kf) >> 15, 8191u);
}

// exclusive prefix over 1024 threads (16 waves of 64). aux: u32[40] LDS.
__device__ __forceinline__ u32 block_exscan_1024(u32 v, u32* aux, u32& total) {
  const int lane = threadIdx.x & 63, wave = threadIdx.x >> 6;
  u32 inc = v;
#pragma unroll
  for (int m = 1; m < 64; m <<= 1) {
    u32 o = (u32)__shfl_up((int)inc, m, 64);
    if (lane >= m) inc += o;
  }
  if (lane == 63) aux[wave] = inc;
  __syncthreads();
  if (wave == 0) {
    u32 wv = (lane < 16) ? aux[lane] : 0u;
    u32 winc = wv;
#pragma unroll
    for (int m = 1; m < 16; m <<= 1) {
      u32 o = (u32)__shfl_up((int)winc, m, 64);
      if (lane >= m) winc += o;
    }
    if (lane < 16) aux[16 + lane] = winc - wv;   // wave-exclusive base
    if (lane == 15) aux[33] = winc;              // grand total
  }
  __syncthreads();
  total = aux[33];
  return aux[16 + wave] + (inc - v);
}

// ===== r2-exact tile128: 2 phases of k=32, loads consumed immediately (NO persistent
// prefetch regs -- r3's spill lesson: 64-acc kernel has no VGPR headroom). =====
__device__ __forceinline__ void tile128(
    const float* __restrict__ X, const float* __restrict__ sq,
    float (*As)[132], float (*Bs)[132],
    int bi, int bj, int tx, int ty, float (&d2)[8][8])
{
  const int tid = threadIdx.x;
  const float4* Xv = reinterpret_cast<const float4*>(X);
  float acc[8][8] = {};
  for (int ph = 0; ph < 2; ++ph) {
    if (ph) __syncthreads();          // protect LDS before overwrite
#pragma unroll
    for (int rep = 0; rep < 4; ++rep) {
      int idx = rep * 256 + tid;      // 0..1023
      int i   = idx >> 3;             // row 0..127
      int q   = idx & 7;              // local k-quad
      int col = (((i >> 2) ^ (q >> 1)) << 2) | (i & 3);   // 2 lanes/bank = free
      float4 va = Xv[(bi * 128 + i) * 16 + ph * 8 + q];
      As[4*q+0][col] = va.x; As[4*q+1][col] = va.y; As[4*q+2][col] = va.z; As[4*q+3][col] = va.w;
      float4 vb = Xv[(bj * 128 + i) * 16 + ph * 8 + q];
      Bs[4*q+0][col] = vb.x; Bs[4*q+1][col] = vb.y; Bs[4*q+2][col] = vb.z; Bs[4*q+3][col] = vb.w;
    }
    __syncthreads();
#pragma unroll
    for (int c8 = 0; c8 < 4; ++c8) {
#pragma unroll
      for (int u = 0; u < 8; ++u) {
        int k = c8 * 8 + u;
        float4 a0 = *reinterpret_cast<const float4*>(&As[k][((2*ty+0) ^ c8) << 2]);
        float4 a1 = *reinterpret_cast<const float4*>(&As[k][((2*ty+1) ^ c8) << 2]);
        float4 b0 = *reinterpret_cast<const float4*>(&Bs[k][((2*tx+0) ^ c8) << 2]);
        float4 b1 = *reinterpret_cast<const float4*>(&Bs[k][((2*tx+1) ^ c8) << 2]);
        float a[8] = {a0.x,a0.y,a0.z,a0.w,a1.x,a1.y,a1.z,a1.w};
        float b[8] = {b0.x,b0.y,b0.z,b0.w,b1.x,b1.y,b1.z,b1.w};
#pragma unroll
        for (int r = 0; r < 8; ++r)
#pragma unroll
          for (int c = 0; c < 8; ++c)
            acc[r][c] = fmaf(a[r], b[c], acc[r][c]);
      }
    }
  }
  float sqa[8], sqb[8];
#pragma unroll
  for (int r = 0; r < 8; ++r) sqa[r] = sq[bi * 128 + ty * 8 + r];
#pragma unroll
  for (int c = 0; c < 8; ++c) sqb[c] = sq[bj * 128 + tx * 8 + c];
#pragma unroll
  for (int r = 0; r < 8; ++r)
#pragma unroll
    for (int c = 0; c < 8; ++c)
      d2[r][c] = fmaxf((sqa[r] + sqb[c]) - 2.0f * acc[r][c], 0.0f);
}

// ===== per-element pass bodies (shared by recompute and stored-d2 kernels) =====

__device__ __forceinline__ void collect_body(
    float (&d2)[8][8], int bi, int bj, int tx, int ty, u32* __restrict__ ws)
{
  u32* st = ws + WS_STATE / 4;
  const u32 b0 = st[0], b1 = st[1];
  u32* ctr = st + 4;
  u64* cand = reinterpret_cast<u64*>((char*)ws + WS_CAND);
  const int ig0 = bi * 128 + ty * 8, jg0 = bj * 128 + tx * 8;
  const bool offd = (bi < bj);
  const int lane = threadIdx.x & 63;
#pragma unroll
  for (int r = 0; r < 8; ++r)
#pragma unroll
    for (int c = 0; c < 8; ++c) {
      int ig = ig0 + r, jg = jg0 + c;
      u32 w = offd ? 2u : (ig < jg ? 2u : (ig == jg ? 1u : 0u));
      u32 bin = bin_of(d2[r][c]);
      bool ic = w && (bin == b0 || bin == b1);
      u64 m = __ballot(ic);
      if (m) {
        int leader = __ffsll((long long)m) - 1;
        u32 base = 0;
        if (lane == leader) base = atomicAdd(ctr, (u32)__popcll(m));
        base = (u32)__shfl((int)base, leader);
        if (ic) {
          u32 pos = base + (u32)__popcll(m & ((1ull << lane) - 1ull));
          if (pos < CAP)
            cand[pos] = (((u64)__float_as_uint(d2[r][c])) << 32) | (u64)w;
        }
      }
    }
}

// rho: A-side 128 atomics (1/row); B-side cross-wave LDS reduce -> 128 atomics (was 512)
__device__ __forceinline__ void rho_body(
    float (&d2)[8][8], int bi, int bj, int tx, int ty, u32* __restrict__ ws)
{
  __shared__ double redB[4][128];   // 4 KB
  const int tid = threadIdx.x;
  const int wv = tid >> 6, lane = tid & 63;
  const float dcf = *reinterpret_cast<const float*>((const char*)ws + WS_DC);
  const float inv2 = 1.0f / (dcf * dcf);
  const int ig0 = bi * 128 + ty * 8, jg0 = bj * 128 + tx * 8;
  const bool diag = (bi == bj);
  float rA[8] = {}, rB[8] = {};
#pragma unroll
  for (int r = 0; r < 8; ++r)
#pragma unroll
    for (int c = 0; c < 8; ++c) {
      float t = __expf(-(d2[r][c] * inv2));
      if (!diag) { rA[r] += t; rB[c] += t; }
      else {
        int ig = ig0 + r, jg = jg0 + c;
        if (ig < jg) { rA[r] += t; rB[c] += t; }
        else if (ig == jg) rA[r] += t;
      }
    }
  double* rhod = reinterpret_cast<double*>((char*)ws + WS_RHOD);
#pragma unroll
  for (int m = 1; m <= 8; m <<= 1)
#pragma unroll
    for (int r = 0; r < 8; ++r) rA[r] += __shfl_xor(rA[r], m);
  if ((tid & 15) == 0)
#pragma unroll
    for (int r = 0; r < 8; ++r) atomicAdd(&rhod[ig0 + r], (double)rA[r]);
#pragma unroll
  for (int m = 16; m <= 32; m <<= 1)
#pragma unroll
    for (int c = 0; c < 8; ++c) rB[c] += __shfl_xor(rB[c], m);
  if (lane < 16)
#pragma unroll
    for (int c = 0; c < 8; ++c) redB[wv][(tid & 15) * 8 + c] = (double)rB[c];
  __syncthreads();
  if (tid < 128) {
    double s = redB[0][tid] + redB[1][tid] + redB[2][tid] + redB[3][tid];
    atomicAdd(&rhod[bj * 128 + tid], s);
  }
}

// delta: same B-side LDS-min reduction (512 -> 128 atomicMin)
__device__ __forceinline__ void delta_body(
    float (&d2)[8][8], int bi, int bj, int tx, int ty, u32* __restrict__ ws)
{
  __shared__ u64 redM[4][128];      // 4 KB
  const int tid = threadIdx.x;
  const int wv = tid >> 6, lane = tid & 63;
  const double* rhod = reinterpret_cast<const double*>((const char*)ws + WS_RHOD);
  const int ig0 = bi * 128 + ty * 8, jg0 = bj * 128 + tx * 8;
  float ri[8], rj[8];
#pragma unroll
  for (int r = 0; r < 8; ++r) ri[r] = (float)rhod[ig0 + r];
#pragma unroll
  for (int c = 0; c < 8; ++c) rj[c] = (float)rhod[jg0 + c];
  u64 bA[8], bB[8];
#pragma unroll
  for (int r = 0; r < 8; ++r) { bA[r] = ~0ull; bB[r] = ~0ull; }
  const bool offd = (bi < bj);
#pragma unroll
  for (int r = 0; r < 8; ++r)
#pragma unroll
    for (int c = 0; c < 8; ++c) {
      int ig = ig0 + r, jg = jg0 + c;
      if (offd || ig < jg) {
        // sqrt: reproduces reference dist-domain argmin tie semantics exactly
        u64 kb = ((u64)__float_as_uint(sqrtf(d2[r][c]))) << 32;
        if (rj[c] > ri[r]) bA[r] = umin64(bA[r], kb | (u64)(u32)jg);
        if (ri[r] > rj[c]) bB[c] = umin64(bB[c], kb | (u64)(u32)ig);
      }
    }
  u64* mk = reinterpret_cast<u64*>((char*)ws + WS_MINKEY);
#pragma unroll
  for (int m = 1; m <= 8; m <<= 1)
#pragma unroll
    for (int r = 0; r < 8; ++r) bA[r] = umin64(bA[r], __shfl_xor(bA[r], m));
  if ((tid & 15) == 0)
#pragma unroll
    for (int r = 0; r < 8; ++r) if (bA[r] != ~0ull) atomicMin(&mk[ig0 + r], bA[r]);
#pragma unroll
  for (int m = 16; m <= 32; m <<= 1)
#pragma unroll
    for (int c = 0; c < 8; ++c) bB[c] = umin64(bB[c], __shfl_xor(bB[c], m));
  if (lane < 16)
#pragma unroll
    for (int c = 0; c < 8; ++c) redM[wv][(tid & 15) * 8 + c] = bB[c];
  __syncthreads();
  if (tid < 128) {
    u64 m = umin64(umin64(redM[0][tid], redM[1][tid]), umin64(redM[2][tid], redM[3][tid]));
    if (m != ~0ull) atomicMin(&mk[bj * 128 + tid], m);
  }
}

// load a stored tile (coalesced: lane-consecutive float4 at fixed q)
__device__ __forceinline__ void load_tile(
    const float4* __restrict__ S4, float (&d2)[8][8])
{
  const float4* tS = S4 + (size_t)blockIdx.x * 4096 + threadIdx.x;
#pragma unroll
  for (int q = 0; q < 16; ++q) {
    float4 v = tS[q * 256];
    int r = q >> 1, c0 = (q & 1) * 4;
    d2[r][c0+0] = v.x; d2[r][c0+1] = v.y; d2[r][c0+2] = v.z; d2[r][c0+3] = v.w;
  }
}

// ===== kernels =====

__global__ __launch_bounds__(256) void k_init(u32* __restrict__ ws) {
  u32 t = blockIdx.x * 256u + threadIdx.x;   // 131072 threads
  ws[t] = 0u;                                // sliced hist
  if (t < 8u) ws[WS_STATE / 4 + t] = 0u;
  if (t < 8192u) {
    ws[WS_ROWMAX / 4 + t] = 0u;
    reinterpret_cast<double*>((char*)ws + WS_RHOD)[t] = 0.0;
    reinterpret_cast<u64*>((char*)ws + WS_MINKEY)[t] = ~0ull;
  }
}

__global__ __launch_bounds__(256) void k_sq(const float* __restrict__ X, float* __restrict__ sq) {
  int i = blockIdx.x * 256 + threadIdx.x;
  const float4* row = reinterpret_cast<const float4*>(X + i * 64);
  float s = 0.f;
#pragma unroll
  for (int q = 0; q < 16; ++q) {
    float4 v = row[q];
    s = fmaf(v.x, v.x, s); s = fmaf(v.y, v.y, s);
    s = fmaf(v.z, v.z, s); s = fmaf(v.w, v.w, s);
  }
  sq[i] = s;   // identical fma chain to tile dot(i,i) -> diagonal d2 == 0 exactly
}

// THE compute pass: d2 tile + d2 store + rowmax + 8192-bin LDS hist -> sliced global flush
__global__ __launch_bounds__(256, 4) void k_hist(
    const float* __restrict__ X, const float* __restrict__ sq,
    u32* __restrict__ ws, float4* __restrict__ S4)
{
  __shared__ __align__(16) char smem[33792];
  float (*As)[132] = reinterpret_cast<float(*)[132]>(smem);
  float (*Bs)[132] = reinterpret_cast<float(*)[132]>(smem + 16896);
  u32* h = reinterpret_cast<u32*>(smem);           // 8192 u32 = 32 KB, reused post-compute
  int bi, bj; tri_decode(blockIdx.x, bi, bj);
  const int tid = threadIdx.x;
  const int tx = tid & 15, ty = tid >> 4;
  float d2[8][8];
  tile128(X, sq, As, Bs, bi, bj, tx, ty, d2);

  if (S4) {                                        // store d2 (coalesced float4)
    float4* tS = S4 + (size_t)blockIdx.x * 4096 + tid;
#pragma unroll
    for (int q = 0; q < 16; ++q) {
      int r = q >> 1, c0 = (q & 1) * 4;
      tS[q * 256] = make_float4(d2[r][c0+0], d2[r][c0+1], d2[r][c0+2], d2[r][c0+3]);
    }
  }

  const int ig0 = bi * 128 + ty * 8, jg0 = bj * 128 + tx * 8;
  u32* rowmax = ws + WS_ROWMAX / 4;
  u32 rmA[8], rmB[8];
#pragma unroll
  for (int r = 0; r < 8; ++r) {
    u32 m = 0;
#pragma unroll
    for (int c = 0; c < 8; ++c) m = max(m, __float_as_uint(d2[r][c]));
    rmA[r] = m;
  }
#pragma unroll
  for (int c = 0; c < 8; ++c) {
    u32 m = 0;
#pragma unroll
    for (int r = 0; r < 8; ++r) m = max(m, __float_as_uint(d2[r][c]));
    rmB[c] = m;
  }
#pragma unroll
  for (int m = 1; m <= 8; m <<= 1)
#pragma unroll
    for (int r = 0; r < 8; ++r) rmA[r] = max(rmA[r], (u32)__shfl_xor((int)rmA[r], m));
  if ((tid & 15) == 0)
#pragma unroll
    for (int r = 0; r < 8; ++r) atomicMax(&rowmax[ig0 + r], rmA[r]);
#pragma unroll
  for (int m = 16; m <= 32; m <<= 1)
#pragma unroll
    for (int c = 0; c < 8; ++c) rmB[c] = max(rmB[c], (u32)__shfl_xor((int)rmB[c], m));
  if ((tid & 48) == 0)
#pragma unroll
    for (int c = 0; c < 8; ++c) atomicMax(&rowmax[jg0 + c], rmB[c]);

  __syncthreads();                                 // done reading tile LDS
  for (int i = tid; i < 8192; i += 256) h[i] = 0;
  __syncthreads();
  const bool offd = (bi < bj);
#pragma unroll
  for (int r = 0; r < 8; ++r)
#pragma unroll
    for (int c = 0; c < 8; ++c) {
      int ig = ig0 + r, jg = jg0 + c;
      u32 w = offd ? 2u : (ig < jg ? 2u : (ig == jg ? 1u : 0u));
      if (w) atomicAdd(&h[bin_of(d2[r][c])], w);
    }
  __syncthreads();
  u32* Hs = ws + (blockIdx.x & 15) * 8192;         // sliced flush: 16x less contention
  for (int b = tid; b < 8192; b += 256) {
    u32 v = h[b];
    if (v) atomicAdd(&Hs[b], v);
  }
}

// parallel: each thread owns 8 bins (sums 16 slices); block exscan; local locate
__global__ __launch_bounds__(1024) void k_sel1(u32* __restrict__ ws) {
  __shared__ u32 aux[40];
  const int t = threadIdx.x;
  const u32* H = ws;
  u32* st = ws + WS_STATE / 4;
  u32 cnt8[8];
  u32 s = 0;
#pragma unroll
  for (int e = 0; e < 8; ++e) {
    u32 b = (u32)t * 8u + (u32)e;
    u32 v = 0;
#pragma unroll
    for (u32 sl = 0; sl < NSLICE; ++sl) v += H[sl * 8192u + b];
    cnt8[e] = v; s += v;
  }
  u32 total;
  u32 cum = block_exscan_1024(s, aux, total);
#pragma unroll
  for (int e = 0; e < 8; ++e) {
    u32 b = (u32)t * 8u + (u32)e;
    u32 c = cnt8[e];
    if (cum <= K_RANK && K_RANK < cum + c)           { st[0] = b; st[2] = cum; }
    if (cum <= K_RANK + 1u && K_RANK + 1u < cum + c) { st[1] = b; st[3] = cum; }
    cum += c;
  }
}

__global__ __launch_bounds__(256, 4) void k_collectR(
    const float* __restrict__ X, const float* __restrict__ sq, u32* __restrict__ ws)
{
  __shared__ __align__(16) char smem[33792];
  float (*As)[132] = reinterpret_cast<float(*)[132]>(smem);
  float (*Bs)[132] = reinterpret_cast<float(*)[132]>(smem + 16896);
  int bi, bj; tri_decode(blockIdx.x, bi, bj);
  const int tx = threadIdx.x & 15, ty = threadIdx.x >> 4;
  float d2[8][8];
  tile128(X, sq, As, Bs, bi, bj, tx, ty, d2);
  collect_body(d2, bi, bj, tx, ty, ws);
}

__global__ __launch_bounds__(256) void k_collectS(
    const float4* __restrict__ S4, u32* __restrict__ ws)
{
  int bi, bj; tri_decode(blockIdx.x, bi, bj);
  const int tx = threadIdx.x & 15, ty = threadIdx.x >> 4;
  float d2[8][8];
  load_tile(S4, d2);
  collect_body(d2, bi, bj, tx, ty, ws);
}

// zoom: LDS histogram refinement over candidate raw bits within bin b.
// bin raw-span ~4100 < 8192 bins => 1 iteration; locate via parallel block scan.
__device__ u32 zoom(const u64* __restrict__ cand, u32 M, u32 b, u32 base, u32 rank,
                    u32* h, u32* aux) {
  u32 lo = __float_as_uint((float)b * 0.03125f);
  u32 hi = __float_as_uint((float)(b + 1) * 0.03125f);
  u32 need = rank - base;
  while (hi - lo > 1u) {
    u32 range = hi - lo;
    int sh = 0;
    while ((8192u << sh) < range) ++sh;
    for (u32 i = threadIdx.x; i < 8192u; i += 1024u) h[i] = 0;
    __syncthreads();
    for (u32 i = threadIdx.x; i < M; i += 1024u) {
      u64 cw = cand[i];
      u32 raw = (u32)(cw >> 32);
      if (raw >= lo && raw < hi) atomicAdd(&h[(raw - lo) >> sh], (u32)(cw & 3u));
    }
    __syncthreads();
    u32 loc[8];
    u32 s = 0;
#pragma unroll
    for (int e = 0; e < 8; ++e) { loc[e] = h[threadIdx.x * 8u + e]; s += loc[e]; }
    u32 total;
    u32 pre = block_exscan_1024(s, aux, total);
    if (need >= pre && need < pre + s) {      // exactly one thread matches
      u32 cum = pre;
#pragma unroll
      for (int e = 0; e < 8; ++e) {
        if (need >= cum && need < cum + loc[e]) { aux[36] = threadIdx.x * 8u + (u32)e; aux[37] = cum; }
        cum += loc[e];
      }
    }
    __syncthreads();
    u32 bb = aux[36], sub = aux[37];
    need -= sub;
    u32 nlo = lo + (bb << sh);
    hi = min(hi, nlo + (1u << sh));
    lo = nlo;
    __syncthreads();
  }
  return lo;
}

__global__ __launch_bounds__(1024) void k_fsel(u32* __restrict__ ws) {
  __shared__ u32 h[8192];
  __shared__ u32 aux[40];
  u32* st = ws + WS_STATE / 4;
  const u64* cand = reinterpret_cast<const u64*>((const char*)ws + WS_CAND);
  u32 M = min(st[4], CAP);
  u32 v0 = zoom(cand, M, st[0], st[2], K_RANK, h, aux);
  u32 v1 = zoom(cand, M, st[1], st[3], K_RANK + 1u, h, aux);
  if (threadIdx.x == 0) {
    float w0 = sqrtf(__uint_as_float(v0));
    float w1 = sqrtf(__uint_as_float(v1));
    double dc = 0.75 * (double)w0 + 0.25 * (double)w1;
    *reinterpret_cast<float*>((char*)ws + WS_DC) = (float)dc;
  }
}

__global__ __launch_bounds__(256, 4) void k_rhoR(
    const float* __restrict__ X, const float* __restrict__ sq, u32* __restrict__ ws)
{
  __shared__ __align__(16) char smem[33792];
  float (*As)[132] = reinterpret_cast<float(*)[132]>(smem);
  float (*Bs)[132] = reinterpret_cast<float(*)[132]>(smem + 16896);
  int bi, bj; tri_decode(blockIdx.x, bi, bj);
  const int tx = threadIdx.x & 15, ty = threadIdx.x >> 4;
  float d2[8][8];
  tile128(X, sq, As, Bs, bi, bj, tx, ty, d2);
  rho_body(d2, bi, bj, tx, ty, ws);
}

__global__ __launch_bounds__(256) void k_rhoS(
    const float4* __restrict__ S4, u32* __restrict__ ws)
{
  int bi, bj; tri_decode(blockIdx.x, bi, bj);
  const int tx = threadIdx.x & 15, ty = threadIdx.x >> 4;
  float d2[8][8];
  load_tile(S4, d2);
  rho_body(d2, bi, bj, tx, ty, ws);
}

__global__ __launch_bounds__(256, 4) void k_deltaR(
    const float* __restrict__ X, const float* __restrict__ sq, u32* __restrict__ ws)
{
  __shared__ __align__(16) char smem[33792];
  float (*As)[132] = reinterpret_cast<float(*)[132]>(smem);
  float (*Bs)[132] = reinterpret_cast<float(*)[132]>(smem + 16896);
  int bi, bj; tri_decode(blockIdx.x, bi, bj);
  const int tx = threadIdx.x & 15, ty = threadIdx.x >> 4;
  float d2[8][8];
  tile128(X, sq, As, Bs, bi, bj, tx, ty, d2);
  delta_body(d2, bi, bj, tx, ty, ws);
}

__global__ __launch_bounds__(256) void k_deltaS(
    const float4* __restrict__ S4, u32* __restrict__ ws)
{
  int bi, bj; tri_decode(blockIdx.x, bi, bj);
  const int tx = threadIdx.x & 15, ty = threadIdx.x >> 4;
  float d2[8][8];
  load_tile(S4, d2);
  delta_body(d2, bi, bj, tx, ty, ws);
}

// labels via pointer doubling: nxt absorbing at labeled nodes / self-loops.
// 13 rounds (2^13 >= 8192); in-place races are benign (any read is a valid ancestor).
__global__ __launch_bounds__(1024) void k_labels(
    const u32* __restrict__ ws, const float* __restrict__ rtp,
    const float* __restrict__ dtp, int* __restrict__ out)
{
  __shared__ int   nxt[NPTS];     // 32 KB
  __shared__ short lab0[NPTS];    // 16 KB
  __shared__ u32   aux[40];
  const int t = threadIdx.x;
  const float rt = rtp[0], dt = dtp[0];
  const u64* mk = reinterpret_cast<const u64*>((const char*)ws + WS_MINKEY);
  const u32* rowmax = ws + WS_ROWMAX / 4;
  const double* rhod = reinterpret_cast<const double*>((const char*)ws + WS_RHOD);
  u32 cnt = 0;
  short loc[8];
  int nh_l[8];
#pragma unroll
  for (int e = 0; e < 8; ++e) {
    int i = t * 8 + e;
    u64 key = mk[i];
    bool hh = (key != ~0ull);
    float delta = hh ? __uint_as_float((u32)(key >> 32))
                     : sqrtf(__uint_as_float(rowmax[i]));
    nh_l[e] = hh ? (int)(u32)(key & 0xffffffffull) : i;
    bool isc = ((float)rhod[i] > rt) && (delta > dt);
    loc[e] = isc ? (short)cnt : (short)-1;
    cnt += isc ? 1u : 0u;
  }
  u32 total;
  u32 base = block_exscan_1024(cnt, aux, total);
#pragma unroll
  for (int e = 0; e < 8; ++e) {
    int i = t * 8 + e;
    short lb = (loc[e] >= 0) ? (short)(loc[e] + (int)base) : (short)-1;
    lab0[i] = lb;
    nxt[i] = (lb >= 0 || nh_l[e] == i) ? i : nh_l[e];
  }
  __syncthreads();
  for (int it = 0; it < 13; ++it) {
#pragma unroll
    for (int e = 0; e < 8; ++e) {
      int i = t * 8 + e;
      nxt[i] = nxt[nxt[i]];
    }
    __syncthreads();
  }
#pragma unroll
  for (int e = 0; e < 8; ++e) {
    int i = t * 8 + e;
    out[i] = (int)lab0[nxt[i]];
  }
}

extern "C" void kernel_launch(void* const* d_in, const int* in_sizes, int n_in,
                              void* d_out, int out_size, void* d_ws, size_t ws_size,
                              hipStream_t stream)
{
  (void)in_sizes; (void)n_in; (void)out_size;
  const float* X  = (const float*)d_in[0];
  const float* rt = (const float*)d_in[1];
  const float* dt = (const float*)d_in[2];
  int* out = (int*)d_out;
  u32* ws = (u32*)d_ws;
  float* sq = (float*)((char*)d_ws + WS_SQ);

  const bool big = ws_size >= (size_t)(WS_S + (u64)NTRI * 16384ull * 4ull);
  float4* S4 = big ? reinterpret_cast<float4*>((char*)d_ws + WS_S) : nullptr;

  k_init<<<512, 256, 0, stream>>>(ws);
  k_sq<<<32, 256, 0, stream>>>(X, sq);

  k_hist<<<NTRI, 256, 0, stream>>>(X, sq, ws, S4);
  k_sel1<<<1, 1024, 0, stream>>>(ws);
  if (big) k_collectS<<<NTRI, 256, 0, stream>>>(S4, ws);
  else     k_collectR<<<NTRI, 256, 0, stream>>>(X, sq, ws);
  k_fsel<<<1, 1024, 0, stream>>>(ws);
  if (big) k_rhoS<<<NTRI, 256, 0, stream>>>(S4, ws);
  else     k_rhoR<<<NTRI, 256, 0, stream>>>(X, sq, ws);
  if (big) k_deltaS<<<NTRI, 256, 0, stream>>>(S4, ws);
  else     k_deltaR<<<NTRI, 256, 0, stream>>>(X, sq, ws);
  k_labels<<<1, 1024, 0, stream>>>(ws, rt, dt, out);
}